// Round 2
// baseline (9678.439 us; speedup 1.0000x reference)
//
#include <hip/hip_runtime.h>
#include <math.h>

#define B_ 8
#define L_ 2048
#define D_ 512
#define M_ 256
#define D2_ 1024
#define H_ 2048
#define N_ 16384          // B_*L_
#define EPS_ 1e-6f
#define RCH_ 1024         // row chunk for yo / FFN phases (16 chunks)

// ---------------------------------------------------------------------------
// Generic fp32 GEMM: C = epi(A @ B), 64x64 tile, BK=16, 256 threads, 4x4/thread.
// If A2 != nullptr: A is the concat [A | A2] along K (each row-major with row
// stride D_=512); lda ignored. (Used to fuse concat(zr,zi) into QKV GEMMs.)
// transA: A stored as (K x rows) row-major. transB: B stored (cols x K).
// epi: 0:*alpha  1:-0.5*rowAux[row]  2:/(rowAux[row]+EPS)  3:relu(+colBias)
//      4:+colBias
// batched via blockIdx.z, strides sA/sB/sC; rowAux index = bz*auxStride+row.
// All dims multiples of tile sizes.
// ---------------------------------------------------------------------------
__global__ __launch_bounds__(256)
void gemm256(const float* __restrict__ A, const float* __restrict__ A2,
             const float* __restrict__ Bm, float* __restrict__ C,
             int K, int lda, int ldb, int ldc,
             long long sA, long long sB, long long sC,
             int transA, int transB, int epi, float alpha,
             const float* __restrict__ rowAux, int auxStride,
             const float* __restrict__ colBias)
{
    const int bz = blockIdx.z;
    A  += (long long)bz * sA;
    Bm += (long long)bz * sB;
    C  += (long long)bz * sC;
    const int row0 = blockIdx.y * 64;
    const int col0 = blockIdx.x * 64;

    __shared__ float As[16][64];
    __shared__ float Bs[16][64];

    const int tid = threadIdx.x;
    const int tx = tid & 15, ty = tid >> 4;
    const int lrow = tid >> 2;          // 0..63   (row-major staging)
    const int lk   = (tid & 3) << 2;    // 0,4,8,12
    const int pk_  = tid >> 4;          // 0..15   (k-major staging)
    const int pc   = (tid & 15) << 2;   // 0..60

    float acc[4][4] = {{0.f}};

    for (int k0 = 0; k0 < K; k0 += 16) {
        if (A2) {
            int col = k0 + lk;
            const float* src = (col < D_)
                ? (A  + (long long)(row0 + lrow) * D_ + col)
                : (A2 + (long long)(row0 + lrow) * D_ + (col - D_));
            float4 a4 = *(const float4*)src;
            As[lk + 0][lrow] = a4.x; As[lk + 1][lrow] = a4.y;
            As[lk + 2][lrow] = a4.z; As[lk + 3][lrow] = a4.w;
        } else if (transA) {
            float4 a4 = *(const float4*)(A + (long long)(k0 + pk_) * lda + row0 + pc);
            *(float4*)&As[pk_][pc] = a4;
        } else {
            float4 a4 = *(const float4*)(A + (long long)(row0 + lrow) * lda + k0 + lk);
            As[lk + 0][lrow] = a4.x; As[lk + 1][lrow] = a4.y;
            As[lk + 2][lrow] = a4.z; As[lk + 3][lrow] = a4.w;
        }
        if (transB) {
            float4 b4 = *(const float4*)(Bm + (long long)(col0 + lrow) * ldb + k0 + lk);
            Bs[lk + 0][lrow] = b4.x; Bs[lk + 1][lrow] = b4.y;
            Bs[lk + 2][lrow] = b4.z; Bs[lk + 3][lrow] = b4.w;
        } else {
            float4 b4 = *(const float4*)(Bm + (long long)(k0 + pk_) * ldb + col0 + pc);
            *(float4*)&Bs[pk_][pc] = b4;
        }
        __syncthreads();
        #pragma unroll
        for (int kk = 0; kk < 16; ++kk) {
            float4 av = *(const float4*)&As[kk][ty << 2];
            float4 bv = *(const float4*)&Bs[kk][tx << 2];
            float a0[4] = {av.x, av.y, av.z, av.w};
            float b0[4] = {bv.x, bv.y, bv.z, bv.w};
            #pragma unroll
            for (int i = 0; i < 4; ++i)
                #pragma unroll
                for (int j = 0; j < 4; ++j)
                    acc[i][j] = fmaf(a0[i], b0[j], acc[i][j]);
        }
        __syncthreads();
    }

    const int rbase = row0 + (ty << 2), cbase = col0 + (tx << 2);
    #pragma unroll
    for (int i = 0; i < 4; ++i) {
        float vals[4];
        float raux = 0.f;
        if (epi == 1 || epi == 2) raux = rowAux[(long long)bz * auxStride + rbase + i];
        #pragma unroll
        for (int j = 0; j < 4; ++j) {
            float v = acc[i][j];
            if (epi == 0)      v *= alpha;
            else if (epi == 1) v = v - 0.5f * raux;
            else if (epi == 2) v = v / (raux + EPS_);
            else if (epi == 3) { v += colBias[cbase + j]; v = v > 0.f ? v : 0.f; }
            else if (epi == 4) v += colBias[cbase + j];
            vals[j] = v;
        }
        float4 o; o.x = vals[0]; o.y = vals[1]; o.z = vals[2]; o.w = vals[3];
        *(float4*)(C + (long long)(rbase + i) * ldc + cbase) = o;
    }
}

// ssq[n] = sum_j A[n,j]^2  (row length D2_), one wave per row
__global__ __launch_bounds__(256)
void rowsumsq(const float* __restrict__ A, float* __restrict__ out)
{
    int wid = threadIdx.x >> 6, lane = threadIdx.x & 63;
    long long row = (long long)blockIdx.x * 4 + wid;
    const float* a = A + row * D2_;
    float s = 0.f;
    #pragma unroll
    for (int it = 0; it < 4; ++it) {
        float4 v = *(const float4*)(a + ((it * 64 + lane) << 2));
        s += v.x * v.x + v.y * v.y + v.z * v.z + v.w * v.w;
    }
    #pragma unroll
    for (int off = 32; off; off >>= 1) s += __shfl_down(s, off, 64);
    if (lane == 0) out[row] = s;
}

// phi_q: per-row (M_) max-subtract + exp, in place. One 256-thread block/row.
__global__ __launch_bounds__(256)
void phi_rowmax_exp(float* __restrict__ P)
{
    const long long row = blockIdx.x;
    const int t = threadIdx.x;
    float v = P[row * M_ + t];
    float m = v;
    #pragma unroll
    for (int off = 32; off; off >>= 1) m = fmaxf(m, __shfl_down(m, off, 64));
    __shared__ float sm[4];
    const int wid = t >> 6, lane = t & 63;
    if (lane == 0) sm[wid] = m;
    __syncthreads();
    const float mm = fmaxf(fmaxf(sm[0], sm[1]), fmaxf(sm[2], sm[3]));
    P[row * M_ + t] = expf(v - mm) * 0.0625f;   // 1/sqrt(M)=1/16
}

__global__ __launch_bounds__(256)
void gmax1(const float* __restrict__ P, float* __restrict__ part, int n)
{
    float m = -3.4e38f;
    for (long long i = (long long)blockIdx.x * 256 + threadIdx.x; i < n;
         i += (long long)gridDim.x * 256)
        m = fmaxf(m, P[i]);
    #pragma unroll
    for (int off = 32; off; off >>= 1) m = fmaxf(m, __shfl_down(m, off, 64));
    __shared__ float sm[4];
    int wid = threadIdx.x >> 6, lane = threadIdx.x & 63;
    if (lane == 0) sm[wid] = m;
    __syncthreads();
    if (threadIdx.x == 0)
        part[blockIdx.x] = fmaxf(fmaxf(sm[0], sm[1]), fmaxf(sm[2], sm[3]));
}

__global__ __launch_bounds__(256)
void gmax2(float* __restrict__ red)
{
    float m = -3.4e38f;
    for (int i = threadIdx.x; i < 1024; i += 256) m = fmaxf(m, red[256 + i]);
    #pragma unroll
    for (int off = 32; off; off >>= 1) m = fmaxf(m, __shfl_down(m, off, 64));
    __shared__ float sm[4];
    int wid = threadIdx.x >> 6, lane = threadIdx.x & 63;
    if (lane == 0) sm[wid] = m;
    __syncthreads();
    if (threadIdx.x == 0) red[0] = fmaxf(fmaxf(sm[0], sm[1]), fmaxf(sm[2], sm[3]));
}

// phi_k = exp(pk - gmax)/16, elementwise in place
__global__ __launch_bounds__(256)
void phik_exp(float* __restrict__ P, const float* __restrict__ red)
{
    long long i = (long long)blockIdx.x * 256 + threadIdx.x;
    float g = red[0];
    P[i] = expf(P[i] - g) * 0.0625f;
}

// ksum[b,m] = sum_l phi_k[b,l,m]; one block per batch, thread per m
__global__ __launch_bounds__(256)
void ksum_k(const float* __restrict__ phik, float* __restrict__ ks)
{
    int b = blockIdx.x, m = threadIdx.x;
    const float* p = phik + (long long)b * L_ * M_ + m;
    float s0 = 0.f, s1 = 0.f, s2 = 0.f, s3 = 0.f;
    for (int l = 0; l < L_; l += 4) {
        s0 += p[(long long)(l + 0) * M_];
        s1 += p[(long long)(l + 1) * M_];
        s2 += p[(long long)(l + 2) * M_];
        s3 += p[(long long)(l + 3) * M_];
    }
    ks[b * M_ + m] = (s0 + s1) + (s2 + s3);
}

// den[n] = sum_m phi_q[n,m]*ksum[b,m]; one wave per row
__global__ __launch_bounds__(256)
void den_k(const float* __restrict__ phiq, const float* __restrict__ ks,
           float* __restrict__ den)
{
    int wid = threadIdx.x >> 6, lane = threadIdx.x & 63;
    long long n = (long long)blockIdx.x * 4 + wid;
    int b = (int)(n >> 11);
    float4 p = *(const float4*)(phiq + n * M_ + (lane << 2));
    float4 kk = *(const float4*)(ks + b * M_ + (lane << 2));
    float s = p.x * kk.x + p.y * kk.y + p.z * kk.z + p.w * kk.w;
    #pragma unroll
    for (int off = 32; off; off >>= 1) s += __shfl_down(s, off, 64);
    if (lane == 0) den[n] = s;
}

// zstate chunk = modrelu(z + yo) stored as rows of (.,D2) = [zr2 | zi2]
// processes RCH_*D_ elements; zr/zi/zst pre-offset to chunk start
__global__ __launch_bounds__(256)
void modrelu_attn(const float* __restrict__ zr, const float* __restrict__ zi,
                  const float* __restrict__ yo, const float* __restrict__ b_attn,
                  float* __restrict__ zst)
{
    long long t = (long long)blockIdx.x * 256 + threadIdx.x;  // over RCH_*D_
    long long n = t >> 9; int d = (int)(t & 511);
    float ar = zr[t] + yo[n * D2_ + d];
    float ai = zi[t] + yo[n * D2_ + D_ + d];
    float mag = sqrtf(ar * ar + ai * ai + EPS_);
    float s = fmaxf(mag + b_attn[d], 0.f) / mag;
    zst[n * D2_ + d]      = ar * s;
    zst[n * D2_ + D_ + d] = ai * s;
}

// Combined FFN1 weight (2D x 2H): [[W1r, W1i], [-W1i, W1r]]; bias bc1
__global__ __launch_bounds__(256)
void build_wc1(const float* __restrict__ W1r, const float* __restrict__ W1i,
               const float* __restrict__ b1r, const float* __restrict__ b1i,
               float* __restrict__ wc1, float* __restrict__ bc1)
{
    long long t = (long long)blockIdx.x * 256 + threadIdx.x;  // 1024*4096
    int i = (int)(t >> 12), j = (int)(t & 4095);
    float v;
    if (j < H_) v = (i < D_) ? W1r[i * H_ + j] : -W1i[(i - D_) * H_ + j];
    else { int jj = j - H_; v = (i < D_) ? W1i[i * H_ + jj] : W1r[(i - D_) * H_ + jj]; }
    wc1[t] = v;
    if (i == 0) bc1[j] = (j < H_) ? b1r[j] : b1i[j - H_];
}

// Combined FFN2 weight (2H x 2D): [[W2r, W2i], [-W2i, W2r]]; bias bc2
__global__ __launch_bounds__(256)
void build_wc2(const float* __restrict__ W2r, const float* __restrict__ W2i,
               const float* __restrict__ b2r, const float* __restrict__ b2i,
               float* __restrict__ wc2, float* __restrict__ bc2)
{
    long long t = (long long)blockIdx.x * 256 + threadIdx.x;  // 4096*1024
    int i = (int)(t >> 10), j = (int)(t & 1023);
    float v;
    if (j < D_) v = (i < H_) ? W2r[i * D_ + j] : -W2i[(i - H_) * D_ + j];
    else { int jj = j - D_; v = (i < H_) ? W2i[i * D_ + jj] : W2r[(i - H_) * D_ + jj]; }
    wc2[t] = v;
    if (i == 0) bc2[j] = (j < D_) ? b2r[j] : b2i[j - D_];
}

// out chunk = modrelu(zstate + f), interleaved; zst/f/out pre-offset
__global__ __launch_bounds__(256)
void modrelu_out(const float* __restrict__ zst, const float* __restrict__ f,
                 const float* __restrict__ b_ffn, float* __restrict__ out)
{
    long long t = (long long)blockIdx.x * 256 + threadIdx.x;  // over RCH_*D_
    long long n = t >> 9; int d = (int)(t & 511);
    float ar = zst[n * D2_ + d]      + f[n * D2_ + d];
    float ai = zst[n * D2_ + D_ + d] + f[n * D2_ + D_ + d];
    float mag = sqrtf(ar * ar + ai * ai + EPS_);
    float s = fmaxf(mag + b_ffn[d], 0.f) / mag;
    out[t * 2]     = ar * s;
    out[t * 2 + 1] = ai * s;
}

extern "C" void kernel_launch(void* const* d_in, const int* in_sizes, int n_in,
                              void* d_out, int out_size, void* d_ws, size_t ws_size,
                              hipStream_t stream)
{
    const float* zr    = (const float*)d_in[0];
    const float* zi    = (const float*)d_in[1];
    const float* Wq    = (const float*)d_in[2];
    const float* Wk    = (const float*)d_in[3];
    const float* Wv    = (const float*)d_in[4];
    const float* Wo    = (const float*)d_in[5];
    const float* Wf    = (const float*)d_in[6];
    const float* b_attn= (const float*)d_in[7];
    const float* W1r   = (const float*)d_in[8];
    const float* W1i   = (const float*)d_in[9];
    const float* b1r   = (const float*)d_in[10];
    const float* b1i   = (const float*)d_in[11];
    const float* W2r   = (const float*)d_in[12];
    const float* W2i   = (const float*)d_in[13];
    const float* b2r   = (const float*)d_in[14];
    const float* b2i   = (const float*)d_in[15];
    const float* b_ffn = (const float*)d_in[16];

    float* ws = (float*)d_ws;
    // Lean lifetime-based layout: 32,564,224 floats = 124.2 MB peak.
    float* Abuf = ws + 0LL;          // (N,D2): q -> k -> v -> y -> zstate
    float* P1   = ws + 16777216LL;   // (N,M) pq/phi_q -> later wc1 (1024x4096)
    float* P2   = ws + 20971520LL;   // (N,M) pk/phi_k -> later wc2 (4096x1024)
    float* KV   = ws + 25165824LL;   // (B,M,D2)
    float* HB   = ws + 27262976LL;   // FFN hidden chunk (RCH_ x 4096)
    float* T    = ws + 31457280LL;   // yo / f chunk (RCH_ x 1024)
    float* ssqq = ws + 32505856LL;   // (N)
    float* ssqk = ws + 32522240LL;   // (N)
    float* den  = ws + 32538624LL;   // (N)
    float* ksum = ws + 32555008LL;   // (B,M)
    float* red  = ws + 32557056LL;   // [0]=gmax, [256..1280)=partials
    float* bc1  = ws + 32559104LL;   // (4096)
    float* bc2  = ws + 32563200LL;   // (1024)

    const float scl = 0.1767766952966369f;  // D2^-0.25
    dim3 blk(256);

    auto G = [&](const float* A, const float* A2, const float* Bm, float* C,
                 int rows, int cols, int K, int lda, int ldb, int ldc,
                 long long sA, long long sB, long long sC, int nb,
                 int tA, int tB, int epi, float alpha,
                 const float* rowAux, int auxStride, const float* colBias) {
        dim3 grid(cols / 64, rows / 64, nb);
        gemm256<<<grid, blk, 0, stream>>>(A, A2, Bm, C, K, lda, ldb, ldc,
                                          sA, sB, sC, tA, tB, epi, alpha,
                                          rowAux, auxStride, colBias);
    };

    // --- q phase: q = [zr|zi]@Wq*scl; ssqq; pq = q@Wf^T - 0.5*ssqq ---
    G(zr, zi, Wq, Abuf, N_, D2_, D2_, D_, D2_, D2_, 0, 0, 0, 1, 0, 0, 0, scl, nullptr, 0, nullptr);
    rowsumsq<<<N_ / 4, blk, 0, stream>>>(Abuf, ssqq);
    G(Abuf, nullptr, Wf, P1, N_, M_, D2_, D2_, D2_, M_, 0, 0, 0, 1, 0, 1, 1, 1.f, ssqq, 0, nullptr);
    // --- k phase ---
    G(zr, zi, Wk, Abuf, N_, D2_, D2_, D_, D2_, D2_, 0, 0, 0, 1, 0, 0, 0, scl, nullptr, 0, nullptr);
    rowsumsq<<<N_ / 4, blk, 0, stream>>>(Abuf, ssqk);
    G(Abuf, nullptr, Wf, P2, N_, M_, D2_, D2_, D2_, M_, 0, 0, 0, 1, 0, 1, 1, 1.f, ssqk, 0, nullptr);
    // --- v ---
    G(zr, zi, Wv, Abuf, N_, D2_, D2_, D_, D2_, D2_, 0, 0, 0, 1, 0, 0, 0, 1.f, nullptr, 0, nullptr);
    // --- feature maps ---
    phi_rowmax_exp<<<N_, blk, 0, stream>>>(P1);
    gmax1<<<1024, blk, 0, stream>>>(P2, red + 256, N_ * M_);
    gmax2<<<1, blk, 0, stream>>>(red);
    phik_exp<<<N_ * M_ / 256, blk, 0, stream>>>(P2, red);
    // --- ksum, kv = phi_k^T @ v (batched, transA) ---
    ksum_k<<<B_, blk, 0, stream>>>(P2, ksum);
    G(P2, nullptr, Abuf, KV, M_, D2_, L_, M_, D2_, D2_,
      (long long)L_ * M_, (long long)L_ * D2_, (long long)M_ * D2_, B_,
      1, 0, 0, 1.f, nullptr, 0, nullptr);
    // --- den; y = (phi_q @ kv)/(den+eps) -> Abuf (v dead) ---
    den_k<<<N_ / 4, blk, 0, stream>>>(P1, ksum, den);
    G(P1, nullptr, KV, Abuf, L_, D2_, M_, M_, D2_, D2_,
      (long long)L_ * M_, (long long)M_ * D2_, (long long)L_ * D2_, B_,
      0, 0, 2, 1.f, den, L_, nullptr);
    // --- combined FFN weights into P1/P2 (phi buffers dead) ---
    build_wc1<<<D2_ * (2 * H_) / 256, blk, 0, stream>>>(W1r, W1i, b1r, b1i, P1, bc1);
    build_wc2<<<(2 * H_) * D2_ / 256, blk, 0, stream>>>(W2r, W2i, b2r, b2i, P2, bc2);
    // --- per chunk: yo = y@Wo -> T; zstate = modrelu(z+yo) -> Abuf in place ---
    for (int c = 0; c < N_ / RCH_; ++c) {
        const long long ro = (long long)c * RCH_;
        G(Abuf + ro * D2_, nullptr, Wo, T, RCH_, D2_, D2_, D2_, D2_, D2_,
          0, 0, 0, 1, 0, 0, 0, 1.f, nullptr, 0, nullptr);
        modrelu_attn<<<RCH_ * D_ / 256, blk, 0, stream>>>(
            zr + ro * D_, zi + ro * D_, T, b_attn, Abuf + ro * D2_);
    }
    // --- per chunk FFN + final modrelu -> out ---
    for (int c = 0; c < N_ / RCH_; ++c) {
        const long long ro = (long long)c * RCH_;
        G(Abuf + ro * D2_, nullptr, P1, HB, RCH_, 2 * H_, D2_, D2_, 2 * H_, 2 * H_,
          0, 0, 0, 1, 0, 0, 3, 1.f, nullptr, 0, bc1);
        G(HB, nullptr, P2, T, RCH_, D2_, 2 * H_, 2 * H_, D2_, D2_,
          0, 0, 0, 1, 0, 0, 4, 1.f, nullptr, 0, bc2);
        modrelu_out<<<RCH_ * D_ / 256, blk, 0, stream>>>(
            Abuf + ro * D2_, T, b_ffn, (float*)d_out + ro * D_ * 2);
    }

    (void)in_sizes; (void)n_in; (void)out_size; (void)ws_size;
}

// Round 3
// 1539.196 us; speedup vs baseline: 6.2880x; 6.2880x over previous
//
#include <hip/hip_runtime.h>
#include <math.h>

#define B_ 8
#define L_ 2048
#define D_ 512
#define M_ 256
#define D2_ 1024
#define H_ 2048
#define N_ 16384          // B_*L_
#define EPS_ 1e-6f

typedef __attribute__((ext_vector_type(8))) short bf16x8;
typedef __attribute__((ext_vector_type(4))) float f32x4;
typedef unsigned short ushort_t;
typedef unsigned int uint_t;

__device__ __forceinline__ ushort_t f2bf(float f) {
    uint_t u = __float_as_uint(f);
    u += 0x7FFFu + ((u >> 16) & 1u);        // round-to-nearest-even
    return (ushort_t)(u >> 16);
}
__device__ __forceinline__ float bf2f(ushort_t u) {
    return __uint_as_float(((uint_t)u) << 16);
}
__device__ __forceinline__ void gload_lds16(const void* g, void* l) {
    __builtin_amdgcn_global_load_lds(
        (const __attribute__((address_space(1))) void*)g,
        (__attribute__((address_space(3))) void*)l, 16, 0, 0);
}

// ---------------------------------------------------------------------------
// bf16 MFMA GEMM, m97 structure: 128x128 tile, BK=32, 256 thr = 2x2 waves,
// each wave 4x4 tiles of mfma_f32_16x16x32_bf16. A:(rows x K) K-contig bf16,
// B:(cols x K) K-contig bf16. Epilogues:
//  0: *alpha   1: -0.5*aux[row]   5: -0.5*aux[col]   2: /(aux[row]+EPS)
//  3: relu(+bias[col])   4: +bias[col].   obf: 1 -> bf16 out, 0 -> fp32 out.
// Batched via blockIdx.z (element strides sA/sB/sC); aux idx = bz*auxStride+.
// rows, cols % 128 == 0; K % 32 == 0.
// ---------------------------------------------------------------------------
__global__ __launch_bounds__(256)
void gemm_mfma(const ushort_t* __restrict__ A, const ushort_t* __restrict__ Bm,
               void* __restrict__ Cp, int K, int lda, int ldb, int ldc,
               long long sA, long long sB, long long sC,
               int epi, float alpha, const float* __restrict__ aux,
               int auxStride, const float* __restrict__ bias, int obf)
{
    __shared__ ushort_t As[128 * 32];
    __shared__ ushort_t Bs[128 * 32];

    const int bz = blockIdx.z;
    A  += (long long)bz * sA;
    Bm += (long long)bz * sB;
    const int row0 = blockIdx.y * 128;
    const int col0 = blockIdx.x * 128;

    const int tid  = threadIdx.x;
    const int lane = tid & 63;
    const int wave = tid >> 6;
    const int wr = wave >> 1, wc = wave & 1;

    // staging: thread covers row (tid>>2), k-col (tid&3)*8 ; 2 issues (+64 rows)
    const int srow = tid >> 2;
    const int skol = (tid & 3) * 8;

    f32x4 acc[4][4];
    #pragma unroll
    for (int i = 0; i < 4; ++i)
        #pragma unroll
        for (int j = 0; j < 4; ++j)
            acc[i][j] = (f32x4){0.f, 0.f, 0.f, 0.f};

    const int fr = lane & 15;     // row/col within 16-tile
    const int fq = lane >> 4;     // k-quad

    for (int k0 = 0; k0 < K; k0 += 32) {
        // A tile: 128 rows x 32 k
        gload_lds16(A + (long long)(row0 + srow) * lda + k0 + skol,
                    &As[(wave * 16) * 32]);
        gload_lds16(A + (long long)(row0 + 64 + srow) * lda + k0 + skol,
                    &As[(64 + wave * 16) * 32]);
        // B tile: 128 cols x 32 k
        gload_lds16(Bm + (long long)(col0 + srow) * ldb + k0 + skol,
                    &Bs[(wave * 16) * 32]);
        gload_lds16(Bm + (long long)(col0 + 64 + srow) * ldb + k0 + skol,
                    &Bs[(64 + wave * 16) * 32]);
        __syncthreads();

        bf16x8 a[4], b[4];
        #pragma unroll
        for (int i = 0; i < 4; ++i)
            a[i] = *(const bf16x8*)&As[(wr * 64 + i * 16 + fr) * 32 + fq * 8];
        #pragma unroll
        for (int j = 0; j < 4; ++j)
            b[j] = *(const bf16x8*)&Bs[(wc * 64 + j * 16 + fr) * 32 + fq * 8];
        #pragma unroll
        for (int i = 0; i < 4; ++i)
            #pragma unroll
            for (int j = 0; j < 4; ++j)
                acc[i][j] = __builtin_amdgcn_mfma_f32_16x16x32_bf16(
                    a[i], b[j], acc[i][j], 0, 0, 0);
        __syncthreads();
    }

    // epilogue: C/D layout col=lane&15, row=(lane>>4)*4+reg
    const int gr0 = row0 + wr * 64;
    const int gc0 = col0 + wc * 64;
    #pragma unroll
    for (int i = 0; i < 4; ++i) {
        #pragma unroll
        for (int r = 0; r < 4; ++r) {
            const int row = gr0 + i * 16 + fq * 4 + r;
            float raux = 0.f;
            if (epi == 1 || epi == 2) raux = aux[(long long)bz * auxStride + row];
            #pragma unroll
            for (int j = 0; j < 4; ++j) {
                const int col = gc0 + j * 16 + fr;
                float v = acc[i][j][r];
                if (epi == 0)      v *= alpha;
                else if (epi == 1) v -= 0.5f * raux;
                else if (epi == 2) v = v / (raux + EPS_);
                else if (epi == 5) v -= 0.5f * aux[(long long)bz * auxStride + col];
                else if (epi == 3) { v += bias[col]; v = v > 0.f ? v : 0.f; }
                else if (epi == 4) v += bias[col];
                const long long off = (long long)bz * sC + (long long)row * ldc + col;
                if (obf) ((ushort_t*)Cp)[off] = f2bf(v);
                else     ((float*)Cp)[off] = v;
            }
        }
    }
}

// ---------- build / convert kernels ----------------------------------------

// 1024x1024 fp32 W -> bf16 W^T  (out[n][k] = W[k][n])
__global__ __launch_bounds__(256)
void transpose_cvt_sq(const float* __restrict__ W, ushort_t* __restrict__ out)
{
    __shared__ float S[32][33];
    const int tx = threadIdx.x & 31, ty = threadIdx.x >> 5;
    const int n0 = blockIdx.x * 32, k0 = blockIdx.y * 32;
    #pragma unroll
    for (int r = 0; r < 4; ++r)
        S[ty + 8 * r][tx] = W[(long long)(k0 + ty + 8 * r) * 1024 + n0 + tx];
    __syncthreads();
    #pragma unroll
    for (int r = 0; r < 4; ++r)
        out[(long long)(n0 + ty + 8 * r) * 1024 + k0 + tx] = f2bf(S[tx][ty + 8 * r]);
}

// wc1T (4096 x 1024): out[j][i] of combined [[W1r,W1i],[-W1i,W1r]]
__global__ __launch_bounds__(256)
void build_wc1T(const float* __restrict__ W1r, const float* __restrict__ W1i,
                ushort_t* __restrict__ out)
{
    __shared__ float S[32][33];
    const int tx = threadIdx.x & 31, ty = threadIdx.x >> 5;
    const int i0 = blockIdx.x * 32, j0 = blockIdx.y * 32;
    #pragma unroll
    for (int r = 0; r < 4; ++r) {
        const int i = i0 + ty + 8 * r, j = j0 + tx;
        float v;
        if (j < H_) v = (i < D_) ? W1r[(long long)i * H_ + j]
                                 : -W1i[(long long)(i - D_) * H_ + j];
        else {
            const int jj = j - H_;
            v = (i < D_) ? W1i[(long long)i * H_ + jj]
                         : W1r[(long long)(i - D_) * H_ + jj];
        }
        S[tx][ty + 8 * r] = v;
    }
    __syncthreads();
    #pragma unroll
    for (int r = 0; r < 4; ++r)
        out[(long long)(j0 + ty + 8 * r) * 1024 + i0 + tx] = f2bf(S[ty + 8 * r][tx]);
}

// wc2T (1024 x 4096): out[j][i] of combined [[W2r,W2i],[-W2i,W2r]]
__global__ __launch_bounds__(256)
void build_wc2T(const float* __restrict__ W2r, const float* __restrict__ W2i,
                ushort_t* __restrict__ out)
{
    __shared__ float S[32][33];
    const int tx = threadIdx.x & 31, ty = threadIdx.x >> 5;
    const int i0 = blockIdx.x * 32, j0 = blockIdx.y * 32;
    #pragma unroll
    for (int r = 0; r < 4; ++r) {
        const int i = i0 + ty + 8 * r, j = j0 + tx;
        float v;
        if (i < H_) v = (j < D_) ? W2r[(long long)i * D_ + j]
                                 : W2i[(long long)i * D_ + (j - D_)];
        else {
            const int ii = i - H_;
            v = (j < D_) ? -W2i[(long long)ii * D_ + j]
                         : W2r[(long long)ii * D_ + (j - D_)];
        }
        S[tx][ty + 8 * r] = v;
    }
    __syncthreads();
    #pragma unroll
    for (int r = 0; r < 4; ++r)
        out[(long long)(j0 + ty + 8 * r) * 4096 + i0 + tx] = f2bf(S[ty + 8 * r][tx]);
}

__global__ __launch_bounds__(256)
void build_bias(const float* __restrict__ b1r, const float* __restrict__ b1i,
                const float* __restrict__ b2r, const float* __restrict__ b2i,
                float* __restrict__ bc1, float* __restrict__ bc2)
{
    const int t = blockIdx.x * 256 + threadIdx.x;   // grid 16 -> t < 4096
    bc1[t] = (t < H_) ? b1r[t] : b1i[t - H_];
    if (t < D2_) bc2[t] = (t < D_) ? b2r[t] : b2i[t - D_];
}

__global__ __launch_bounds__(256)
void cvt_Wf(const float* __restrict__ Wf, ushort_t* __restrict__ out)
{
    const int t = blockIdx.x * 256 + threadIdx.x;   // 262144
    out[t] = f2bf(Wf[t]);
}

// x_bf (N x D2) = bf16(concat(zr, zi))
__global__ __launch_bounds__(256)
void cvt_x(const float* __restrict__ zr, const float* __restrict__ zi,
           ushort_t* __restrict__ x)
{
    long long t = (long long)blockIdx.x * 256 + threadIdx.x;  // N*D2/4
    long long n = t >> 8;
    int j4 = (int)(t & 255) << 2;
    float4 v;
    if (j4 < D_) v = *(const float4*)(zr + n * D_ + j4);
    else         v = *(const float4*)(zi + n * D_ + (j4 - D_));
    uint2 o;
    o.x = (uint_t)f2bf(v.x) | ((uint_t)f2bf(v.y) << 16);
    o.y = (uint_t)f2bf(v.z) | ((uint_t)f2bf(v.w) << 16);
    *(uint2*)(x + n * D2_ + j4) = o;
}

// ssq[n] = sum_k bf2f(A[n,k])^2, row len 1024, one wave per row
__global__ __launch_bounds__(256)
void rowsumsq_bf(const ushort_t* __restrict__ A, float* __restrict__ out)
{
    const int wid = threadIdx.x >> 6, lane = threadIdx.x & 63;
    const long long row = (long long)blockIdx.x * 4 + wid;
    const ushort_t* a = A + row * D2_;
    float s = 0.f;
    #pragma unroll
    for (int h = 0; h < 2; ++h) {
        uint4 u = *(const uint4*)(a + h * 512 + lane * 8);
        const uint_t w[4] = {u.x, u.y, u.z, u.w};
        #pragma unroll
        for (int p = 0; p < 4; ++p) {
            float lo = bf2f((ushort_t)(w[p] & 0xffff));
            float hi = bf2f((ushort_t)(w[p] >> 16));
            s += lo * lo + hi * hi;
        }
    }
    #pragma unroll
    for (int off = 32; off; off >>= 1) s += __shfl_down(s, off, 64);
    if (lane == 0) out[row] = s;
}

// phi_q: per-row max-subtract + exp over M=256, pq fp32 -> bf16 out
__global__ __launch_bounds__(256)
void phi_rowmax_exp(const float* __restrict__ P, ushort_t* __restrict__ out)
{
    const long long row = blockIdx.x;
    const int t = threadIdx.x;
    const float v = P[row * M_ + t];
    float m = v;
    #pragma unroll
    for (int off = 32; off; off >>= 1) m = fmaxf(m, __shfl_down(m, off, 64));
    __shared__ float sm[4];
    const int wid = t >> 6, lane = t & 63;
    if (lane == 0) sm[wid] = m;
    __syncthreads();
    const float mm = fmaxf(fmaxf(sm[0], sm[1]), fmaxf(sm[2], sm[3]));
    out[row * M_ + t] = f2bf(expf(v - mm) * 0.0625f);
}

__global__ __launch_bounds__(256)
void gmax1(const float* __restrict__ P, float* __restrict__ part, int n)
{
    float m = -3.4e38f;
    for (long long i = (long long)blockIdx.x * 256 + threadIdx.x; i < n;
         i += (long long)gridDim.x * 256)
        m = fmaxf(m, P[i]);
    #pragma unroll
    for (int off = 32; off; off >>= 1) m = fmaxf(m, __shfl_down(m, off, 64));
    __shared__ float sm[4];
    const int wid = threadIdx.x >> 6, lane = threadIdx.x & 63;
    if (lane == 0) sm[wid] = m;
    __syncthreads();
    if (threadIdx.x == 0)
        part[blockIdx.x] = fmaxf(fmaxf(sm[0], sm[1]), fmaxf(sm[2], sm[3]));
}

__global__ __launch_bounds__(256)
void gmax2(float* __restrict__ red)
{
    float m = -3.4e38f;
    for (int i = threadIdx.x; i < 1024; i += 256) m = fmaxf(m, red[256 + i]);
    #pragma unroll
    for (int off = 32; off; off >>= 1) m = fmaxf(m, __shfl_down(m, off, 64));
    __shared__ float sm[4];
    const int wid = threadIdx.x >> 6, lane = threadIdx.x & 63;
    if (lane == 0) sm[wid] = m;
    __syncthreads();
    if (threadIdx.x == 0) red[0] = fmaxf(fmaxf(sm[0], sm[1]), fmaxf(sm[2], sm[3]));
}

// phi_kT = bf16(exp(pkT - gmax)/16)
__global__ __launch_bounds__(256)
void phikT_exp(const float* __restrict__ P, const float* __restrict__ red,
               ushort_t* __restrict__ out)
{
    const long long i = (long long)blockIdx.x * 256 + threadIdx.x;
    out[i] = f2bf(expf(P[i] - red[0]) * 0.0625f);
}

// ksum[b,m] = sum_l phi_kT[m, b*L+l]; one block per (b,m)
__global__ __launch_bounds__(256)
void ksum_k(const ushort_t* __restrict__ phikT, float* __restrict__ ks)
{
    const int b = blockIdx.x >> 8, m = blockIdx.x & 255;
    const ushort_t* p = phikT + (long long)m * N_ + b * L_;
    uint4 u = *(const uint4*)(p + threadIdx.x * 8);
    const uint_t w[4] = {u.x, u.y, u.z, u.w};
    float s = 0.f;
    #pragma unroll
    for (int q = 0; q < 4; ++q)
        s += bf2f((ushort_t)(w[q] & 0xffff)) + bf2f((ushort_t)(w[q] >> 16));
    #pragma unroll
    for (int off = 32; off; off >>= 1) s += __shfl_down(s, off, 64);
    __shared__ float sm[4];
    const int wid = threadIdx.x >> 6, lane = threadIdx.x & 63;
    if (lane == 0) sm[wid] = s;
    __syncthreads();
    if (threadIdx.x == 0)
        ks[blockIdx.x] = sm[0] + sm[1] + sm[2] + sm[3];
}

// den[n] = sum_m phi_q_bf[n,m]*ksum[b,m]; one wave per row
__global__ __launch_bounds__(256)
void den_k(const ushort_t* __restrict__ phiq, const float* __restrict__ ks,
           float* __restrict__ den)
{
    const int wid = threadIdx.x >> 6, lane = threadIdx.x & 63;
    const long long n = (long long)blockIdx.x * 4 + wid;
    const int b = (int)(n >> 11);
    uint2 u = *(const uint2*)(phiq + n * M_ + lane * 4);
    float4 kk = *(const float4*)(ks + b * M_ + lane * 4);
    float s = bf2f((ushort_t)(u.x & 0xffff)) * kk.x
            + bf2f((ushort_t)(u.x >> 16)) * kk.y
            + bf2f((ushort_t)(u.y & 0xffff)) * kk.z
            + bf2f((ushort_t)(u.y >> 16)) * kk.w;
    #pragma unroll
    for (int off = 32; off; off >>= 1) s += __shfl_down(s, off, 64);
    if (lane == 0) den[n] = s;
}

// zst_bf chunk = bf16(modrelu(z + yo)); zr/zi/out pre-offset; yo chunk-local
__global__ __launch_bounds__(256)
void modrelu_attn(const float* __restrict__ zr, const float* __restrict__ zi,
                  const float* __restrict__ yo, const float* __restrict__ b_attn,
                  ushort_t* __restrict__ zst)
{
    const long long t = (long long)blockIdx.x * 256 + threadIdx.x;
    const long long n = t >> 9; const int d = (int)(t & 511);
    const float ar = zr[t] + yo[n * D2_ + d];
    const float ai = zi[t] + yo[n * D2_ + D_ + d];
    const float mag = sqrtf(ar * ar + ai * ai + EPS_);
    const float s = fmaxf(mag + b_attn[d], 0.f) / mag;
    zst[n * D2_ + d]      = f2bf(ar * s);
    zst[n * D2_ + D_ + d] = f2bf(ai * s);
}

// out chunk = modrelu(zst + f) interleaved; zst(bf16)/f/out pre-offset
__global__ __launch_bounds__(256)
void modrelu_out(const ushort_t* __restrict__ zst, const float* __restrict__ f,
                 const float* __restrict__ b_ffn, float* __restrict__ out)
{
    const long long t = (long long)blockIdx.x * 256 + threadIdx.x;
    const long long n = t >> 9; const int d = (int)(t & 511);
    const float ar = bf2f(zst[n * D2_ + d])      + f[n * D2_ + d];
    const float ai = bf2f(zst[n * D2_ + D_ + d]) + f[n * D2_ + D_ + d];
    const float mag = sqrtf(ar * ar + ai * ai + EPS_);
    const float s = fmaxf(mag + b_ffn[d], 0.f) / mag;
    out[t * 2]     = ar * s;
    out[t * 2 + 1] = ai * s;
}

extern "C" void kernel_launch(void* const* d_in, const int* in_sizes, int n_in,
                              void* d_out, int out_size, void* d_ws, size_t ws_size,
                              hipStream_t stream)
{
    const float* zr    = (const float*)d_in[0];
    const float* zi    = (const float*)d_in[1];
    const float* Wq    = (const float*)d_in[2];
    const float* Wk    = (const float*)d_in[3];
    const float* Wv    = (const float*)d_in[4];
    const float* Wo    = (const float*)d_in[5];
    const float* Wf    = (const float*)d_in[6];
    const float* b_attn= (const float*)d_in[7];
    const float* W1r   = (const float*)d_in[8];
    const float* W1i   = (const float*)d_in[9];
    const float* b1r   = (const float*)d_in[10];
    const float* b1i   = (const float*)d_in[11];
    const float* W2r   = (const float*)d_in[12];
    const float* W2i   = (const float*)d_in[13];
    const float* b2r   = (const float*)d_in[14];
    const float* b2i   = (const float*)d_in[15];
    const float* b_ffn = (const float*)d_in[16];

    char* w = (char*)d_ws;
    // Lifetime-reuse layout, 108.7 MB peak (round-2's 124 MB fit fine).
    ushort_t* Xbf = (ushort_t*)(w + 0LL);          // x_bf -> zst_bf (33.55 MB)
    ushort_t* A1  = (ushort_t*)(w + 33554432LL);   // q/k -> vT -> y -> h (33.55 MB)
    float*    P   = (float*)   (w + 67108864LL);   // pq/pkT -> yo/f chunks (16.78 MB)
    ushort_t* F1  = (ushort_t*)(w + 83886080LL);   // phi_q_bf -> wc1T (8.39 MB)
    ushort_t* F2  = (ushort_t*)(w + 92274688LL);   // phi_kT -> wc2T (8.39 MB)
    ushort_t* WqT = (ushort_t*)(w + 100663296LL);
    ushort_t* WkT = (ushort_t*)(w + 102760448LL);
    ushort_t* WvT = (ushort_t*)(w + 104857600LL);
    ushort_t* WoT = (ushort_t*)(w + 106954752LL);
    ushort_t* Wfb = (ushort_t*)(w + 109051904LL);
    ushort_t* KVT = (ushort_t*)(w + 109576192LL);  // (8,1024,256) bf16
    float* ssqq = (float*)(w + 113770496LL);
    float* ssqk = (float*)(w + 113836032LL);
    float* den  = (float*)(w + 113901568LL);
    float* ksum = (float*)(w + 113967104LL);
    float* red  = (float*)(w + 113975296LL);
    float* bc1  = (float*)(w + 113983488LL);
    float* bc2  = (float*)(w + 113999872LL);

    const float scl = 0.1767766952966369f;  // D2^-0.25
    dim3 blk(256);

    auto GM = [&](const ushort_t* A, const ushort_t* Bm, void* C,
                  int rows, int cols, int K, int lda, int ldb, int ldc,
                  long long sA, long long sB, long long sC, int nb,
                  int epi, float alpha, const float* aux, int auxStride,
                  const float* bias, int obf) {
        dim3 grid(cols / 128, rows / 128, nb);
        gemm_mfma<<<grid, blk, 0, stream>>>(A, Bm, C, K, lda, ldb, ldc,
                                            sA, sB, sC, epi, alpha, aux,
                                            auxStride, bias, obf);
    };

    // ---- one-time weight prep + input convert ----
    transpose_cvt_sq<<<dim3(32, 32), blk, 0, stream>>>(Wq, WqT);
    transpose_cvt_sq<<<dim3(32, 32), blk, 0, stream>>>(Wk, WkT);
    transpose_cvt_sq<<<dim3(32, 32), blk, 0, stream>>>(Wv, WvT);
    transpose_cvt_sq<<<dim3(32, 32), blk, 0, stream>>>(Wo, WoT);
    cvt_Wf<<<1024, blk, 0, stream>>>(Wf, Wfb);
    build_bias<<<16, blk, 0, stream>>>(b1r, b1i, b2r, b2i, bc1, bc2);
    cvt_x<<<N_ * (D2_ / 4) / 256, blk, 0, stream>>>(zr, zi, Xbf);

    // ---- q phase: q_bf = x@WqT*scl; ssqq; pq = q@Wf^T - 0.5ssqq; phi_q ----
    GM(Xbf, WqT, A1, N_, D2_, D2_, D2_, D2_, D2_, 0, 0, 0, 1, 0, scl, nullptr, 0, nullptr, 1);
    rowsumsq_bf<<<N_ / 4, blk, 0, stream>>>(A1, ssqq);
    GM(A1, Wfb, P, N_, M_, D2_, D2_, D2_, M_, 0, 0, 0, 1, 1, 1.f, ssqq, 0, nullptr, 0);
    phi_rowmax_exp<<<N_, blk, 0, stream>>>(P, F1);

    // ---- k phase: k_bf; ssqk; pkT = Wf@k^T - 0.5ssqk[col]; phi_kT ----
    GM(Xbf, WkT, A1, N_, D2_, D2_, D2_, D2_, D2_, 0, 0, 0, 1, 0, scl, nullptr, 0, nullptr, 1);
    rowsumsq_bf<<<N_ / 4, blk, 0, stream>>>(A1, ssqk);
    GM(Wfb, A1, P, M_, N_, D2_, D2_, D2_, N_, 0, 0, 0, 1, 5, 1.f, ssqk, 0, nullptr, 0);
    gmax1<<<1024, blk, 0, stream>>>(P, red + 256, M_ * N_);
    gmax2<<<1, blk, 0, stream>>>(red);
    phikT_exp<<<M_ * N_ / 256, blk, 0, stream>>>(P, red, F2);

    // ---- vT = Wv^T @ x^T (1024 x 16384) ----
    GM(WvT, Xbf, A1, D2_, N_, D2_, D2_, D2_, N_, 0, 0, 0, 1, 0, 1.f, nullptr, 0, nullptr, 1);

    // ---- ksum; kvT[b] = vT_b @ phi_kT_b^T (1024 x 256, K=L) ----
    ksum_k<<<B_ * M_, blk, 0, stream>>>(F2, ksum);
    GM(A1, F2, KVT, D2_, M_, L_, N_, N_, M_, L_, L_, (long long)D2_ * M_, B_,
       0, 1.f, nullptr, 0, nullptr, 1);

    // ---- den; y_bf[b] = phi_q_b @ kvT_b^T / (den+eps) ----
    den_k<<<N_ / 4, blk, 0, stream>>>(F1, ksum, den);
    GM(F1, KVT, A1, L_, D2_, M_, M_, M_, D2_, (long long)L_ * M_,
       (long long)D2_ * M_, (long long)L_ * D2_, B_, 2, 1.f, den, L_, nullptr, 1);

    // ---- combined FFN weights into F1/F2 (phi buffers dead) ----
    build_wc1T<<<dim3(32, 128), blk, 0, stream>>>(W1r, W1i, F1);
    build_wc2T<<<dim3(128, 32), blk, 0, stream>>>(W2r, W2i, F2);

    // ---- yo + attn modrelu, 4 chunks of 4096 rows ----
    for (int c = 0; c < 4; ++c) {
        const long long ro = (long long)c * 4096;
        GM(A1 + ro * D2_, WoT, P, 4096, D2_, D2_, D2_, D2_, D2_, 0, 0, 0, 1,
           0, 1.f, nullptr, 0, nullptr, 0);
        modrelu_attn<<<4096 * D_ / 256, blk, 0, stream>>>(
            zr + ro * D_, zi + ro * D_, P, b_attn, Xbf + ro * D2_);
    }
    // ---- FFN + final modrelu, 4 chunks ----
    for (int c = 0; c < 4; ++c) {
        const long long ro = (long long)c * 4096;
        GM(Xbf + ro * D2_, F1, A1, 4096, 2 * H_, D2_, D2_, D2_, 2 * H_,
           0, 0, 0, 1, 3, 1.f, nullptr, 0, bc1, 1);
        GM(A1, F2, P, 4096, D2_, 2 * H_, 2 * H_, 2 * H_, D2_,
           0, 0, 0, 1, 4, 1.f, nullptr, 0, bc2, 0);
        modrelu_out<<<4096 * D_ / 256, blk, 0, stream>>>(
            Xbf + ro * D2_, P, b_ffn, (float*)d_out + ro * D2_);
    }

    (void)in_sizes; (void)n_in; (void)out_size; (void)ws_size;
}

// Round 4
// 1525.945 us; speedup vs baseline: 6.3426x; 1.0087x over previous
//
#include <hip/hip_runtime.h>
#include <math.h>

#define B_ 8
#define L_ 2048
#define D_ 512
#define M_ 256
#define D2_ 1024
#define H_ 2048
#define N_ 16384          // B_*L_
#define EPS_ 1e-6f

typedef __attribute__((ext_vector_type(8))) short bf16x8;
typedef __attribute__((ext_vector_type(4))) float f32x4;
typedef unsigned short ushort_t;
typedef unsigned int uint_t;

__device__ __forceinline__ ushort_t f2bf(float f) {
    uint_t u = __float_as_uint(f);
    u += 0x7FFFu + ((u >> 16) & 1u);        // round-to-nearest-even
    return (ushort_t)(u >> 16);
}
__device__ __forceinline__ float bf2f(ushort_t u) {
    return __uint_as_float(((uint_t)u) << 16);
}
__device__ __forceinline__ void gload_lds16(const void* g, void* l) {
    __builtin_amdgcn_global_load_lds(
        (const __attribute__((address_space(1))) void*)g,
        (__attribute__((address_space(3))) void*)l, 16, 0, 0);
}

// ---------------------------------------------------------------------------
// bf16 MFMA GEMM, m97 structure: 128x128 tile, BK=32, 256 thr = 2x2 waves,
// each wave 4x4 tiles of mfma_f32_16x16x32_bf16. A:(rows x K) K-contig bf16,
// B:(cols x K) K-contig bf16.
// LDS k-chunk XOR swizzle: lane l stages global k-chunk (l&3)^((l>>3)&3) so
// fragment ds_read_b128s spread over all 8 bank groups (2-way = free, m136);
// un-swizzled layout was 8-way conflicted (4.2e6 SQ_LDS_BANK_CONFLICT).
// Epilogues: 0:*alpha 1:-0.5*aux[row] 5:-0.5*aux[col] 2:/(aux[row]+EPS)
//            3:relu(+bias[col]) 4:+bias[col].  obf: 1 bf16 out, 0 fp32 out.
// Batched via blockIdx.z (element strides sA/sB/sC); aux idx = bz*auxStride+.
// rows, cols % 128 == 0; K % 32 == 0.
// ---------------------------------------------------------------------------
__global__ __launch_bounds__(256)
void gemm_mfma(const ushort_t* __restrict__ A, const ushort_t* __restrict__ Bm,
               void* __restrict__ Cp, int K, int lda, int ldb, int ldc,
               long long sA, long long sB, long long sC,
               int epi, float alpha, const float* __restrict__ aux,
               int auxStride, const float* __restrict__ bias, int obf)
{
    __shared__ ushort_t As[128 * 32];
    __shared__ ushort_t Bs[128 * 32];

    const int bz = blockIdx.z;
    A  += (long long)bz * sA;
    Bm += (long long)bz * sB;
    const int row0 = blockIdx.y * 128;
    const int col0 = blockIdx.x * 128;

    const int tid  = threadIdx.x;
    const int lane = tid & 63;
    const int wave = tid >> 6;
    const int wr = wave >> 1, wc = wave & 1;

    // staging: lane covers tile-row (tid>>2); k-chunk swizzled by row:
    // s(row) = (row>>1)&3 ; row = tid>>2 (+64 for second issue, same s)
    const int srow = tid >> 2;
    const int skol = (((tid & 3) ^ ((tid >> 3) & 3)) * 8);

    f32x4 acc[4][4];
    #pragma unroll
    for (int i = 0; i < 4; ++i)
        #pragma unroll
        for (int j = 0; j < 4; ++j)
            acc[i][j] = (f32x4){0.f, 0.f, 0.f, 0.f};

    const int fr = lane & 15;     // row/col within 16-tile
    const int fq = lane >> 4;     // k-quad
    const int sw = (fr >> 1) & 3; // read-side swizzle (lane-constant)
    const int koff = (fq ^ sw) * 8;

    for (int k0 = 0; k0 < K; k0 += 32) {
        // A tile: 128 rows x 32 k
        gload_lds16(A + (long long)(row0 + srow) * lda + k0 + skol,
                    &As[(wave * 16) * 32]);
        gload_lds16(A + (long long)(row0 + 64 + srow) * lda + k0 + skol,
                    &As[(64 + wave * 16) * 32]);
        // B tile: 128 cols x 32 k
        gload_lds16(Bm + (long long)(col0 + srow) * ldb + k0 + skol,
                    &Bs[(wave * 16) * 32]);
        gload_lds16(Bm + (long long)(col0 + 64 + srow) * ldb + k0 + skol,
                    &Bs[(64 + wave * 16) * 32]);
        __syncthreads();

        bf16x8 a[4], b[4];
        #pragma unroll
        for (int i = 0; i < 4; ++i)
            a[i] = *(const bf16x8*)&As[(wr * 64 + i * 16 + fr) * 32 + koff];
        #pragma unroll
        for (int j = 0; j < 4; ++j)
            b[j] = *(const bf16x8*)&Bs[(wc * 64 + j * 16 + fr) * 32 + koff];
        #pragma unroll
        for (int i = 0; i < 4; ++i)
            #pragma unroll
            for (int j = 0; j < 4; ++j)
                acc[i][j] = __builtin_amdgcn_mfma_f32_16x16x32_bf16(
                    a[i], b[j], acc[i][j], 0, 0, 0);
        __syncthreads();
    }

    // epilogue: C/D layout col=lane&15, row=(lane>>4)*4+reg
    const int gr0 = row0 + wr * 64;
    const int gc0 = col0 + wc * 64;
    #pragma unroll
    for (int i = 0; i < 4; ++i) {
        #pragma unroll
        for (int r = 0; r < 4; ++r) {
            const int row = gr0 + i * 16 + fq * 4 + r;
            float raux = 0.f;
            if (epi == 1 || epi == 2) raux = aux[(long long)bz * auxStride + row];
            #pragma unroll
            for (int j = 0; j < 4; ++j) {
                const int col = gc0 + j * 16 + fr;
                float v = acc[i][j][r];
                if (epi == 0)      v *= alpha;
                else if (epi == 1) v -= 0.5f * raux;
                else if (epi == 2) v = v / (raux + EPS_);
                else if (epi == 5) v -= 0.5f * aux[(long long)bz * auxStride + col];
                else if (epi == 3) { v += bias[col]; v = v > 0.f ? v : 0.f; }
                else if (epi == 4) v += bias[col];
                const long long off = (long long)bz * sC + (long long)row * ldc + col;
                if (obf) ((ushort_t*)Cp)[off] = f2bf(v);
                else     ((float*)Cp)[off] = v;
            }
        }
    }
}

// ---------- build / convert kernels ----------------------------------------

// 1024x1024 fp32 W -> bf16 W^T  (out[n][k] = W[k][n])
__global__ __launch_bounds__(256)
void transpose_cvt_sq(const float* __restrict__ W, ushort_t* __restrict__ out)
{
    __shared__ float S[32][33];
    const int tx = threadIdx.x & 31, ty = threadIdx.x >> 5;
    const int n0 = blockIdx.x * 32, k0 = blockIdx.y * 32;
    #pragma unroll
    for (int r = 0; r < 4; ++r)
        S[ty + 8 * r][tx] = W[(long long)(k0 + ty + 8 * r) * 1024 + n0 + tx];
    __syncthreads();
    #pragma unroll
    for (int r = 0; r < 4; ++r)
        out[(long long)(n0 + ty + 8 * r) * 1024 + k0 + tx] = f2bf(S[tx][ty + 8 * r]);
}

// wc1T (4096 x 1024): out[j][i] of combined [[W1r,W1i],[-W1i,W1r]]
__global__ __launch_bounds__(256)
void build_wc1T(const float* __restrict__ W1r, const float* __restrict__ W1i,
                ushort_t* __restrict__ out)
{
    __shared__ float S[32][33];
    const int tx = threadIdx.x & 31, ty = threadIdx.x >> 5;
    const int i0 = blockIdx.x * 32, j0 = blockIdx.y * 32;
    #pragma unroll
    for (int r = 0; r < 4; ++r) {
        const int i = i0 + ty + 8 * r, j = j0 + tx;
        float v;
        if (j < H_) v = (i < D_) ? W1r[(long long)i * H_ + j]
                                 : -W1i[(long long)(i - D_) * H_ + j];
        else {
            const int jj = j - H_;
            v = (i < D_) ? W1i[(long long)i * H_ + jj]
                         : W1r[(long long)(i - D_) * H_ + jj];
        }
        S[tx][ty + 8 * r] = v;
    }
    __syncthreads();
    #pragma unroll
    for (int r = 0; r < 4; ++r)
        out[(long long)(j0 + ty + 8 * r) * 1024 + i0 + tx] = f2bf(S[ty + 8 * r][tx]);
}

// wc2T (1024 x 4096): out[j][i] of combined [[W2r,W2i],[-W2i,W2r]]
__global__ __launch_bounds__(256)
void build_wc2T(const float* __restrict__ W2r, const float* __restrict__ W2i,
                ushort_t* __restrict__ out)
{
    __shared__ float S[32][33];
    const int tx = threadIdx.x & 31, ty = threadIdx.x >> 5;
    const int i0 = blockIdx.x * 32, j0 = blockIdx.y * 32;
    #pragma unroll
    for (int r = 0; r < 4; ++r) {
        const int i = i0 + ty + 8 * r, j = j0 + tx;
        float v;
        if (i < H_) v = (j < D_) ? W2r[(long long)i * D_ + j]
                                 : W2i[(long long)i * D_ + (j - D_)];
        else {
            const int ii = i - H_;
            v = (j < D_) ? -W2i[(long long)ii * D_ + j]
                         : W2r[(long long)ii * D_ + (j - D_)];
        }
        S[tx][ty + 8 * r] = v;
    }
    __syncthreads();
    #pragma unroll
    for (int r = 0; r < 4; ++r)
        out[(long long)(j0 + ty + 8 * r) * 4096 + i0 + tx] = f2bf(S[ty + 8 * r][tx]);
}

__global__ __launch_bounds__(256)
void build_bias(const float* __restrict__ b1r, const float* __restrict__ b1i,
                const float* __restrict__ b2r, const float* __restrict__ b2i,
                float* __restrict__ bc1, float* __restrict__ bc2)
{
    const int t = blockIdx.x * 256 + threadIdx.x;   // grid 16 -> t < 4096
    bc1[t] = (t < H_) ? b1r[t] : b1i[t - H_];
    if (t < D2_) bc2[t] = (t < D_) ? b2r[t] : b2i[t - D_];
}

__global__ __launch_bounds__(256)
void cvt_Wf(const float* __restrict__ Wf, ushort_t* __restrict__ out)
{
    const int t = blockIdx.x * 256 + threadIdx.x;   // 262144
    out[t] = f2bf(Wf[t]);
}

// x_bf (N x D2) = bf16(concat(zr, zi))
__global__ __launch_bounds__(256)
void cvt_x(const float* __restrict__ zr, const float* __restrict__ zi,
           ushort_t* __restrict__ x)
{
    long long t = (long long)blockIdx.x * 256 + threadIdx.x;  // N*D2/4
    long long n = t >> 8;
    int j4 = (int)(t & 255) << 2;
    float4 v;
    if (j4 < D_) v = *(const float4*)(zr + n * D_ + j4);
    else         v = *(const float4*)(zi + n * D_ + (j4 - D_));
    uint2 o;
    o.x = (uint_t)f2bf(v.x) | ((uint_t)f2bf(v.y) << 16);
    o.y = (uint_t)f2bf(v.z) | ((uint_t)f2bf(v.w) << 16);
    *(uint2*)(x + n * D2_ + j4) = o;
}

// ssq[n] = sum_k bf2f(A[n,k])^2, row len 1024, one wave per row
__global__ __launch_bounds__(256)
void rowsumsq_bf(const ushort_t* __restrict__ A, float* __restrict__ out)
{
    const int wid = threadIdx.x >> 6, lane = threadIdx.x & 63;
    const long long row = (long long)blockIdx.x * 4 + wid;
    const ushort_t* a = A + row * D2_;
    float s = 0.f;
    #pragma unroll
    for (int h = 0; h < 2; ++h) {
        uint4 u = *(const uint4*)(a + h * 512 + lane * 8);
        const uint_t w[4] = {u.x, u.y, u.z, u.w};
        #pragma unroll
        for (int p = 0; p < 4; ++p) {
            float lo = bf2f((ushort_t)(w[p] & 0xffff));
            float hi = bf2f((ushort_t)(w[p] >> 16));
            s += lo * lo + hi * hi;
        }
    }
    #pragma unroll
    for (int off = 32; off; off >>= 1) s += __shfl_down(s, off, 64);
    if (lane == 0) out[row] = s;
}

// phi_q: per-row max-subtract + exp over M=256, pq fp32 -> bf16 out
__global__ __launch_bounds__(256)
void phi_rowmax_exp(const float* __restrict__ P, ushort_t* __restrict__ out)
{
    const long long row = blockIdx.x;
    const int t = threadIdx.x;
    const float v = P[row * M_ + t];
    float m = v;
    #pragma unroll
    for (int off = 32; off; off >>= 1) m = fmaxf(m, __shfl_down(m, off, 64));
    __shared__ float sm[4];
    const int wid = t >> 6, lane = t & 63;
    if (lane == 0) sm[wid] = m;
    __syncthreads();
    const float mm = fmaxf(fmaxf(sm[0], sm[1]), fmaxf(sm[2], sm[3]));
    out[row * M_ + t] = f2bf(expf(v - mm) * 0.0625f);
}

__global__ __launch_bounds__(256)
void gmax1(const float* __restrict__ P, float* __restrict__ part, int n)
{
    float m = -3.4e38f;
    for (long long i = (long long)blockIdx.x * 256 + threadIdx.x; i < n;
         i += (long long)gridDim.x * 256)
        m = fmaxf(m, P[i]);
    #pragma unroll
    for (int off = 32; off; off >>= 1) m = fmaxf(m, __shfl_down(m, off, 64));
    __shared__ float sm[4];
    const int wid = threadIdx.x >> 6, lane = threadIdx.x & 63;
    if (lane == 0) sm[wid] = m;
    __syncthreads();
    if (threadIdx.x == 0)
        part[blockIdx.x] = fmaxf(fmaxf(sm[0], sm[1]), fmaxf(sm[2], sm[3]));
}

__global__ __launch_bounds__(256)
void gmax2(float* __restrict__ red)
{
    float m = -3.4e38f;
    for (int i = threadIdx.x; i < 1024; i += 256) m = fmaxf(m, red[256 + i]);
    #pragma unroll
    for (int off = 32; off; off >>= 1) m = fmaxf(m, __shfl_down(m, off, 64));
    __shared__ float sm[4];
    const int wid = threadIdx.x >> 6, lane = threadIdx.x & 63;
    if (lane == 0) sm[wid] = m;
    __syncthreads();
    if (threadIdx.x == 0) red[0] = fmaxf(fmaxf(sm[0], sm[1]), fmaxf(sm[2], sm[3]));
}

// phi_kT = bf16(exp(pkT - gmax)/16)
__global__ __launch_bounds__(256)
void phikT_exp(const float* __restrict__ P, const float* __restrict__ red,
               ushort_t* __restrict__ out)
{
    const long long i = (long long)blockIdx.x * 256 + threadIdx.x;
    out[i] = f2bf(expf(P[i] - red[0]) * 0.0625f);
}

// ksum[b,m] = sum_l phi_kT[m, b*L+l]; one block per (b,m)
__global__ __launch_bounds__(256)
void ksum_k(const ushort_t* __restrict__ phikT, float* __restrict__ ks)
{
    const int b = blockIdx.x >> 8, m = blockIdx.x & 255;
    const ushort_t* p = phikT + (long long)m * N_ + b * L_;
    uint4 u = *(const uint4*)(p + threadIdx.x * 8);
    const uint_t w[4] = {u.x, u.y, u.z, u.w};
    float s = 0.f;
    #pragma unroll
    for (int q = 0; q < 4; ++q)
        s += bf2f((ushort_t)(w[q] & 0xffff)) + bf2f((ushort_t)(w[q] >> 16));
    #pragma unroll
    for (int off = 32; off; off >>= 1) s += __shfl_down(s, off, 64);
    __shared__ float sm[4];
    const int wid = threadIdx.x >> 6, lane = threadIdx.x & 63;
    if (lane == 0) sm[wid] = s;
    __syncthreads();
    if (threadIdx.x == 0)
        ks[blockIdx.x] = sm[0] + sm[1] + sm[2] + sm[3];
}

// den[n] = sum_m phi_q_bf[n,m]*ksum[b,m]; one wave per row
__global__ __launch_bounds__(256)
void den_k(const ushort_t* __restrict__ phiq, const float* __restrict__ ks,
           float* __restrict__ den)
{
    const int wid = threadIdx.x >> 6, lane = threadIdx.x & 63;
    const long long n = (long long)blockIdx.x * 4 + wid;
    const int b = (int)(n >> 11);
    uint2 u = *(const uint2*)(phiq + n * M_ + lane * 4);
    float4 kk = *(const float4*)(ks + b * M_ + lane * 4);
    float s = bf2f((ushort_t)(u.x & 0xffff)) * kk.x
            + bf2f((ushort_t)(u.x >> 16)) * kk.y
            + bf2f((ushort_t)(u.y & 0xffff)) * kk.z
            + bf2f((ushort_t)(u.y >> 16)) * kk.w;
    #pragma unroll
    for (int off = 32; off; off >>= 1) s += __shfl_down(s, off, 64);
    if (lane == 0) den[n] = s;
}

// zst_bf chunk = bf16(modrelu(z + yo)); zr/zi/out pre-offset; yo chunk-local
__global__ __launch_bounds__(256)
void modrelu_attn(const float* __restrict__ zr, const float* __restrict__ zi,
                  const float* __restrict__ yo, const float* __restrict__ b_attn,
                  ushort_t* __restrict__ zst)
{
    const long long t = (long long)blockIdx.x * 256 + threadIdx.x;
    const long long n = t >> 9; const int d = (int)(t & 511);
    const float ar = zr[t] + yo[n * D2_ + d];
    const float ai = zi[t] + yo[n * D2_ + D_ + d];
    const float mag = sqrtf(ar * ar + ai * ai + EPS_);
    const float s = fmaxf(mag + b_attn[d], 0.f) / mag;
    zst[n * D2_ + d]      = f2bf(ar * s);
    zst[n * D2_ + D_ + d] = f2bf(ai * s);
}

// out chunk = modrelu(zst + f) interleaved; zst(bf16)/f/out pre-offset
__global__ __launch_bounds__(256)
void modrelu_out(const ushort_t* __restrict__ zst, const float* __restrict__ f,
                 const float* __restrict__ b_ffn, float* __restrict__ out)
{
    const long long t = (long long)blockIdx.x * 256 + threadIdx.x;
    const long long n = t >> 9; const int d = (int)(t & 511);
    const float ar = bf2f(zst[n * D2_ + d])      + f[n * D2_ + d];
    const float ai = bf2f(zst[n * D2_ + D_ + d]) + f[n * D2_ + D_ + d];
    const float mag = sqrtf(ar * ar + ai * ai + EPS_);
    const float s = fmaxf(mag + b_ffn[d], 0.f) / mag;
    out[t * 2]     = ar * s;
    out[t * 2 + 1] = ai * s;
}

extern "C" void kernel_launch(void* const* d_in, const int* in_sizes, int n_in,
                              void* d_out, int out_size, void* d_ws, size_t ws_size,
                              hipStream_t stream)
{
    const float* zr    = (const float*)d_in[0];
    const float* zi    = (const float*)d_in[1];
    const float* Wq    = (const float*)d_in[2];
    const float* Wk    = (const float*)d_in[3];
    const float* Wv    = (const float*)d_in[4];
    const float* Wo    = (const float*)d_in[5];
    const float* Wf    = (const float*)d_in[6];
    const float* b_attn= (const float*)d_in[7];
    const float* W1r   = (const float*)d_in[8];
    const float* W1i   = (const float*)d_in[9];
    const float* b1r   = (const float*)d_in[10];
    const float* b1i   = (const float*)d_in[11];
    const float* W2r   = (const float*)d_in[12];
    const float* W2i   = (const float*)d_in[13];
    const float* b2r   = (const float*)d_in[14];
    const float* b2i   = (const float*)d_in[15];
    const float* b_ffn = (const float*)d_in[16];

    char* w = (char*)d_ws;
    // Lifetime-reuse layout, 108.7 MB peak.
    ushort_t* Xbf = (ushort_t*)(w + 0LL);          // x_bf -> zst_bf (33.55 MB)
    ushort_t* A1  = (ushort_t*)(w + 33554432LL);   // q/k -> vT -> y -> h (33.55 MB)
    float*    P   = (float*)   (w + 67108864LL);   // pq/pkT -> yo/f chunks (16.78 MB)
    ushort_t* F1  = (ushort_t*)(w + 83886080LL);   // phi_q_bf -> wc1T (8.39 MB)
    ushort_t* F2  = (ushort_t*)(w + 92274688LL);   // phi_kT -> wc2T (8.39 MB)
    ushort_t* WqT = (ushort_t*)(w + 100663296LL);
    ushort_t* WkT = (ushort_t*)(w + 102760448LL);
    ushort_t* WvT = (ushort_t*)(w + 104857600LL);
    ushort_t* WoT = (ushort_t*)(w + 106954752LL);
    ushort_t* Wfb = (ushort_t*)(w + 109051904LL);
    ushort_t* KVT = (ushort_t*)(w + 109576192LL);  // (8,1024,256) bf16
    float* ssqq = (float*)(w + 113770496LL);
    float* ssqk = (float*)(w + 113836032LL);
    float* den  = (float*)(w + 113901568LL);
    float* ksum = (float*)(w + 113967104LL);
    float* red  = (float*)(w + 113975296LL);
    float* bc1  = (float*)(w + 113983488LL);
    float* bc2  = (float*)(w + 113999872LL);

    const float scl = 0.1767766952966369f;  // D2^-0.25
    dim3 blk(256);

    auto GM = [&](const ushort_t* A, const ushort_t* Bm, void* C,
                  int rows, int cols, int K, int lda, int ldb, int ldc,
                  long long sA, long long sB, long long sC, int nb,
                  int epi, float alpha, const float* aux, int auxStride,
                  const float* bias, int obf) {
        dim3 grid(cols / 128, rows / 128, nb);
        gemm_mfma<<<grid, blk, 0, stream>>>(A, Bm, C, K, lda, ldb, ldc,
                                            sA, sB, sC, epi, alpha, aux,
                                            auxStride, bias, obf);
    };

    // ---- one-time weight prep + input convert ----
    transpose_cvt_sq<<<dim3(32, 32), blk, 0, stream>>>(Wq, WqT);
    transpose_cvt_sq<<<dim3(32, 32), blk, 0, stream>>>(Wk, WkT);
    transpose_cvt_sq<<<dim3(32, 32), blk, 0, stream>>>(Wv, WvT);
    transpose_cvt_sq<<<dim3(32, 32), blk, 0, stream>>>(Wo, WoT);
    cvt_Wf<<<1024, blk, 0, stream>>>(Wf, Wfb);
    build_bias<<<16, blk, 0, stream>>>(b1r, b1i, b2r, b2i, bc1, bc2);
    cvt_x<<<N_ * (D2_ / 4) / 256, blk, 0, stream>>>(zr, zi, Xbf);

    // ---- q phase: q_bf = x@WqT*scl; ssqq; pq = q@Wf^T - 0.5ssqq; phi_q ----
    GM(Xbf, WqT, A1, N_, D2_, D2_, D2_, D2_, D2_, 0, 0, 0, 1, 0, scl, nullptr, 0, nullptr, 1);
    rowsumsq_bf<<<N_ / 4, blk, 0, stream>>>(A1, ssqq);
    GM(A1, Wfb, P, N_, M_, D2_, D2_, D2_, M_, 0, 0, 0, 1, 1, 1.f, ssqq, 0, nullptr, 0);
    phi_rowmax_exp<<<N_, blk, 0, stream>>>(P, F1);

    // ---- k phase: k_bf; ssqk; pkT = Wf@k^T - 0.5ssqk[col]; phi_kT ----
    GM(Xbf, WkT, A1, N_, D2_, D2_, D2_, D2_, D2_, 0, 0, 0, 1, 0, scl, nullptr, 0, nullptr, 1);
    rowsumsq_bf<<<N_ / 4, blk, 0, stream>>>(A1, ssqk);
    GM(Wfb, A1, P, M_, N_, D2_, D2_, D2_, N_, 0, 0, 0, 1, 5, 1.f, ssqk, 0, nullptr, 0);
    gmax1<<<1024, blk, 0, stream>>>(P, red + 256, M_ * N_);
    gmax2<<<1, blk, 0, stream>>>(red);
    phikT_exp<<<M_ * N_ / 256, blk, 0, stream>>>(P, red, F2);

    // ---- vT = Wv^T @ x^T (1024 x 16384) ----
    GM(WvT, Xbf, A1, D2_, N_, D2_, D2_, D2_, N_, 0, 0, 0, 1, 0, 1.f, nullptr, 0, nullptr, 1);

    // ---- ksum; kvT[b] = vT_b @ phi_kT_b^T (1024 x 256, K=L) ----
    ksum_k<<<B_ * M_, blk, 0, stream>>>(F2, ksum);
    GM(A1, F2, KVT, D2_, M_, L_, N_, N_, M_, L_, L_, (long long)D2_ * M_, B_,
       0, 1.f, nullptr, 0, nullptr, 1);

    // ---- den; y_bf[b] = phi_q_b @ kvT_b^T / (den+eps) ----
    den_k<<<N_ / 4, blk, 0, stream>>>(F1, ksum, den);
    GM(F1, KVT, A1, L_, D2_, M_, M_, M_, D2_, (long long)L_ * M_,
       (long long)D2_ * M_, (long long)L_ * D2_, B_, 2, 1.f, den, L_, nullptr, 1);

    // ---- combined FFN weights into F1/F2 (phi buffers dead) ----
    build_wc1T<<<dim3(32, 128), blk, 0, stream>>>(W1r, W1i, F1);
    build_wc2T<<<dim3(128, 32), blk, 0, stream>>>(W2r, W2i, F2);

    // ---- yo + attn modrelu, 4 chunks of 4096 rows ----
    for (int c = 0; c < 4; ++c) {
        const long long ro = (long long)c * 4096;
        GM(A1 + ro * D2_, WoT, P, 4096, D2_, D2_, D2_, D2_, D2_, 0, 0, 0, 1,
           0, 1.f, nullptr, 0, nullptr, 0);
        modrelu_attn<<<4096 * D_ / 256, blk, 0, stream>>>(
            zr + ro * D_, zi + ro * D_, P, b_attn, Xbf + ro * D2_);
    }
    // ---- FFN + final modrelu, 4 chunks ----
    for (int c = 0; c < 4; ++c) {
        const long long ro = (long long)c * 4096;
        GM(Xbf + ro * D2_, F1, A1, 4096, 2 * H_, D2_, D2_, D2_, 2 * H_,
           0, 0, 0, 1, 3, 1.f, nullptr, 0, bc1, 1);
        GM(A1, F2, P, 4096, D2_, 2 * H_, 2 * H_, 2 * H_, D2_,
           0, 0, 0, 1, 4, 1.f, nullptr, 0, bc2, 0);
        modrelu_out<<<4096 * D_ / 256, blk, 0, stream>>>(
            Xbf + ro * D2_, P, b_ffn, (float*)d_out + ro * D2_);
    }

    (void)in_sizes; (void)n_in; (void)out_size; (void)ws_size;
}

// Round 5
// 1320.283 us; speedup vs baseline: 7.3306x; 1.1558x over previous
//
#include <hip/hip_runtime.h>
#include <math.h>

#define B_ 8
#define L_ 2048
#define D_ 512
#define M_ 256
#define D2_ 1024
#define H_ 2048
#define N_ 16384          // B_*L_
#define EPS_ 1e-6f

typedef __attribute__((ext_vector_type(8))) short bf16x8;
typedef __attribute__((ext_vector_type(4))) float f32x4;
typedef unsigned short ushort_t;
typedef unsigned int uint_t;

// s_waitcnt immediates: lgkmcnt=0xF (no wait), expcnt=7 (no wait), vmcnt=N
#define WAITCNT_VM4 0x0F74
#define WAITCNT_VM0 0x0F70

__device__ __forceinline__ ushort_t f2bf(float f) {
    uint_t u = __float_as_uint(f);
    u += 0x7FFFu + ((u >> 16) & 1u);        // round-to-nearest-even
    return (ushort_t)(u >> 16);
}
__device__ __forceinline__ float bf2f(ushort_t u) {
    return __uint_as_float(((uint_t)u) << 16);
}
__device__ __forceinline__ void gload_lds16(const void* g, void* l) {
    __builtin_amdgcn_global_load_lds(
        (const __attribute__((address_space(1))) void*)g,
        (__attribute__((address_space(3))) void*)l, 16, 0, 0);
}

// ---------------------------------------------------------------------------
// bf16 MFMA GEMM: 128x128 tile, BK=32, 256 thr = 2x2 waves, 4x4 16x16x32 MFMA
// per wave. A:(rows x K) K-contig bf16, B:(cols x K) K-contig bf16.
// DOUBLE-BUFFERED K-loop (m139/AITER pattern): issue next tile's
// global_load_lds into the other LDS buffer, then s_waitcnt vmcnt(4) (current
// tile done, next still in flight) + s_barrier. At 1 block/CU the single-buf
// vmcnt(0) drain serialized ~250-300cyc/K-step (MfmaUtil 12%); dbuf overlaps
// staging with compute.
// LDS k-chunk XOR swizzle (round-3): staging lane l takes global k-chunk
// (l&3)^((l>>3)&3); fragment reads use (fq^((fr>>1)&3)) -> 0 bank conflicts.
// Epilogues: 0:*alpha 1:-0.5*aux[row] 5:-0.5*aux[col] 2:/(aux[row]+EPS)
//            3:relu(+bias[col]) 4:+bias[col].  obf: 1 bf16 out, 0 fp32 out.
// Batched via blockIdx.z (element strides sA/sB/sC); aux idx = bz*auxStride+.
// rows, cols % 128 == 0; K % 32 == 0, K/32 >= 2.
// ---------------------------------------------------------------------------
__global__ __launch_bounds__(256)
void gemm_mfma(const ushort_t* __restrict__ A, const ushort_t* __restrict__ Bm,
               void* __restrict__ Cp, int K, int lda, int ldb, int ldc,
               long long sA, long long sB, long long sC,
               int epi, float alpha, const float* __restrict__ aux,
               int auxStride, const float* __restrict__ bias, int obf)
{
    __shared__ ushort_t As[2][128 * 32];
    __shared__ ushort_t Bs[2][128 * 32];

    const int bz = blockIdx.z;
    A  += (long long)bz * sA;
    Bm += (long long)bz * sB;
    const int row0 = blockIdx.y * 128;
    const int col0 = blockIdx.x * 128;

    const int tid  = threadIdx.x;
    const int lane = tid & 63;
    const int wave = tid >> 6;
    const int wr = wave >> 1, wc = wave & 1;

    const int srow = tid >> 2;
    const int skol = (((tid & 3) ^ ((tid >> 3) & 3)) * 8);

    f32x4 acc[4][4];
    #pragma unroll
    for (int i = 0; i < 4; ++i)
        #pragma unroll
        for (int j = 0; j < 4; ++j)
            acc[i][j] = (f32x4){0.f, 0.f, 0.f, 0.f};

    const int fr = lane & 15;     // row/col within 16-tile
    const int fq = lane >> 4;     // k-quad
    const int koff = ((fq ^ ((fr >> 1) & 3))) * 8;

    const int nT = K >> 5;

    auto issue = [&](int k0, int buf) {
        gload_lds16(A + (long long)(row0 + srow) * lda + k0 + skol,
                    &As[buf][(wave * 16) * 32]);
        gload_lds16(A + (long long)(row0 + 64 + srow) * lda + k0 + skol,
                    &As[buf][(64 + wave * 16) * 32]);
        gload_lds16(Bm + (long long)(col0 + srow) * ldb + k0 + skol,
                    &Bs[buf][(wave * 16) * 32]);
        gload_lds16(Bm + (long long)(col0 + 64 + srow) * ldb + k0 + skol,
                    &Bs[buf][(64 + wave * 16) * 32]);
    };

    issue(0, 0);
    for (int t = 0; t < nT; ++t) {
        const int cur = t & 1;
        if (t + 1 < nT) {
            issue((t + 1) << 5, cur ^ 1);
            __builtin_amdgcn_s_waitcnt(WAITCNT_VM4);  // cur tile landed
        } else {
            __builtin_amdgcn_s_waitcnt(WAITCNT_VM0);
        }
        __builtin_amdgcn_s_barrier();

        bf16x8 a[4], b[4];
        #pragma unroll
        for (int i = 0; i < 4; ++i)
            a[i] = *(const bf16x8*)&As[cur][(wr * 64 + i * 16 + fr) * 32 + koff];
        #pragma unroll
        for (int j = 0; j < 4; ++j)
            b[j] = *(const bf16x8*)&Bs[cur][(wc * 64 + j * 16 + fr) * 32 + koff];
        #pragma unroll
        for (int i = 0; i < 4; ++i)
            #pragma unroll
            for (int j = 0; j < 4; ++j)
                acc[i][j] = __builtin_amdgcn_mfma_f32_16x16x32_bf16(
                    a[i], b[j], acc[i][j], 0, 0, 0);

        __builtin_amdgcn_s_barrier();  // all reads of buf 'cur' done before
                                       // next iter overwrites it
    }

    // epilogue: C/D layout col=lane&15, row=(lane>>4)*4+reg
    const int gr0 = row0 + wr * 64;
    const int gc0 = col0 + wc * 64;
    #pragma unroll
    for (int i = 0; i < 4; ++i) {
        #pragma unroll
        for (int r = 0; r < 4; ++r) {
            const int row = gr0 + i * 16 + fq * 4 + r;
            float raux = 0.f;
            if (epi == 1 || epi == 2) raux = aux[(long long)bz * auxStride + row];
            #pragma unroll
            for (int j = 0; j < 4; ++j) {
                const int col = gc0 + j * 16 + fr;
                float v = acc[i][j][r];
                if (epi == 0)      v *= alpha;
                else if (epi == 1) v -= 0.5f * raux;
                else if (epi == 2) v = v / (raux + EPS_);
                else if (epi == 5) v -= 0.5f * aux[(long long)bz * auxStride + col];
                else if (epi == 3) { v += bias[col]; v = v > 0.f ? v : 0.f; }
                else if (epi == 4) v += bias[col];
                const long long off = (long long)bz * sC + (long long)row * ldc + col;
                if (obf) ((ushort_t*)Cp)[off] = f2bf(v);
                else     ((float*)Cp)[off] = v;
            }
        }
    }
}

// ---------- build / convert kernels ----------------------------------------

// 1024x1024 fp32 W -> bf16 W^T  (out[n][k] = W[k][n])
__global__ __launch_bounds__(256)
void transpose_cvt_sq(const float* __restrict__ W, ushort_t* __restrict__ out)
{
    __shared__ float S[32][33];
    const int tx = threadIdx.x & 31, ty = threadIdx.x >> 5;
    const int n0 = blockIdx.x * 32, k0 = blockIdx.y * 32;
    #pragma unroll
    for (int r = 0; r < 4; ++r)
        S[ty + 8 * r][tx] = W[(long long)(k0 + ty + 8 * r) * 1024 + n0 + tx];
    __syncthreads();
    #pragma unroll
    for (int r = 0; r < 4; ++r)
        out[(long long)(n0 + ty + 8 * r) * 1024 + k0 + tx] = f2bf(S[tx][ty + 8 * r]);
}

// wc1T (4096 x 1024): out[j][i] of combined [[W1r,W1i],[-W1i,W1r]]
__global__ __launch_bounds__(256)
void build_wc1T(const float* __restrict__ W1r, const float* __restrict__ W1i,
                ushort_t* __restrict__ out)
{
    __shared__ float S[32][33];
    const int tx = threadIdx.x & 31, ty = threadIdx.x >> 5;
    const int i0 = blockIdx.x * 32, j0 = blockIdx.y * 32;
    #pragma unroll
    for (int r = 0; r < 4; ++r) {
        const int i = i0 + ty + 8 * r, j = j0 + tx;
        float v;
        if (j < H_) v = (i < D_) ? W1r[(long long)i * H_ + j]
                                 : -W1i[(long long)(i - D_) * H_ + j];
        else {
            const int jj = j - H_;
            v = (i < D_) ? W1i[(long long)i * H_ + jj]
                         : W1r[(long long)(i - D_) * H_ + jj];
        }
        S[tx][ty + 8 * r] = v;
    }
    __syncthreads();
    #pragma unroll
    for (int r = 0; r < 4; ++r)
        out[(long long)(j0 + ty + 8 * r) * 1024 + i0 + tx] = f2bf(S[ty + 8 * r][tx]);
}

// wc2T (1024 x 4096): out[j][i] of combined [[W2r,W2i],[-W2i,W2r]]
__global__ __launch_bounds__(256)
void build_wc2T(const float* __restrict__ W2r, const float* __restrict__ W2i,
                ushort_t* __restrict__ out)
{
    __shared__ float S[32][33];
    const int tx = threadIdx.x & 31, ty = threadIdx.x >> 5;
    const int i0 = blockIdx.x * 32, j0 = blockIdx.y * 32;
    #pragma unroll
    for (int r = 0; r < 4; ++r) {
        const int i = i0 + ty + 8 * r, j = j0 + tx;
        float v;
        if (i < H_) v = (j < D_) ? W2r[(long long)i * D_ + j]
                                 : W2i[(long long)i * D_ + (j - D_)];
        else {
            const int ii = i - H_;
            v = (j < D_) ? -W2i[(long long)ii * D_ + j]
                         : W2r[(long long)ii * D_ + (j - D_)];
        }
        S[tx][ty + 8 * r] = v;
    }
    __syncthreads();
    #pragma unroll
    for (int r = 0; r < 4; ++r)
        out[(long long)(j0 + ty + 8 * r) * 4096 + i0 + tx] = f2bf(S[ty + 8 * r][tx]);
}

__global__ __launch_bounds__(256)
void build_bias(const float* __restrict__ b1r, const float* __restrict__ b1i,
                const float* __restrict__ b2r, const float* __restrict__ b2i,
                float* __restrict__ bc1, float* __restrict__ bc2)
{
    const int t = blockIdx.x * 256 + threadIdx.x;   // grid 16 -> t < 4096
    bc1[t] = (t < H_) ? b1r[t] : b1i[t - H_];
    if (t < D2_) bc2[t] = (t < D_) ? b2r[t] : b2i[t - D_];
}

__global__ __launch_bounds__(256)
void cvt_Wf(const float* __restrict__ Wf, ushort_t* __restrict__ out)
{
    const int t = blockIdx.x * 256 + threadIdx.x;   // 262144
    out[t] = f2bf(Wf[t]);
}

// x_bf (N x D2) = bf16(concat(zr, zi))
__global__ __launch_bounds__(256)
void cvt_x(const float* __restrict__ zr, const float* __restrict__ zi,
           ushort_t* __restrict__ x)
{
    long long t = (long long)blockIdx.x * 256 + threadIdx.x;  // N*D2/4
    long long n = t >> 8;
    int j4 = (int)(t & 255) << 2;
    float4 v;
    if (j4 < D_) v = *(const float4*)(zr + n * D_ + j4);
    else         v = *(const float4*)(zi + n * D_ + (j4 - D_));
    uint2 o;
    o.x = (uint_t)f2bf(v.x) | ((uint_t)f2bf(v.y) << 16);
    o.y = (uint_t)f2bf(v.z) | ((uint_t)f2bf(v.w) << 16);
    *(uint2*)(x + n * D2_ + j4) = o;
}

// ssq[n] = sum_k bf2f(A[n,k])^2, row len 1024, one wave per row
__global__ __launch_bounds__(256)
void rowsumsq_bf(const ushort_t* __restrict__ A, float* __restrict__ out)
{
    const int wid = threadIdx.x >> 6, lane = threadIdx.x & 63;
    const long long row = (long long)blockIdx.x * 4 + wid;
    const ushort_t* a = A + row * D2_;
    float s = 0.f;
    #pragma unroll
    for (int h = 0; h < 2; ++h) {
        uint4 u = *(const uint4*)(a + h * 512 + lane * 8);
        const uint_t w[4] = {u.x, u.y, u.z, u.w};
        #pragma unroll
        for (int p = 0; p < 4; ++p) {
            float lo = bf2f((ushort_t)(w[p] & 0xffff));
            float hi = bf2f((ushort_t)(w[p] >> 16));
            s += lo * lo + hi * hi;
        }
    }
    #pragma unroll
    for (int off = 32; off; off >>= 1) s += __shfl_down(s, off, 64);
    if (lane == 0) out[row] = s;
}

// phi_q: per-row max-subtract + exp over M=256, pq fp32 -> bf16 out
__global__ __launch_bounds__(256)
void phi_rowmax_exp(const float* __restrict__ P, ushort_t* __restrict__ out)
{
    const long long row = blockIdx.x;
    const int t = threadIdx.x;
    const float v = P[row * M_ + t];
    float m = v;
    #pragma unroll
    for (int off = 32; off; off >>= 1) m = fmaxf(m, __shfl_down(m, off, 64));
    __shared__ float sm[4];
    const int wid = t >> 6, lane = t & 63;
    if (lane == 0) sm[wid] = m;
    __syncthreads();
    const float mm = fmaxf(fmaxf(sm[0], sm[1]), fmaxf(sm[2], sm[3]));
    out[row * M_ + t] = f2bf(expf(v - mm) * 0.0625f);
}

__global__ __launch_bounds__(256)
void gmax1(const float* __restrict__ P, float* __restrict__ part, int n)
{
    float m = -3.4e38f;
    for (long long i = (long long)blockIdx.x * 256 + threadIdx.x; i < n;
         i += (long long)gridDim.x * 256)
        m = fmaxf(m, P[i]);
    #pragma unroll
    for (int off = 32; off; off >>= 1) m = fmaxf(m, __shfl_down(m, off, 64));
    __shared__ float sm[4];
    const int wid = threadIdx.x >> 6, lane = threadIdx.x & 63;
    if (lane == 0) sm[wid] = m;
    __syncthreads();
    if (threadIdx.x == 0)
        part[blockIdx.x] = fmaxf(fmaxf(sm[0], sm[1]), fmaxf(sm[2], sm[3]));
}

__global__ __launch_bounds__(256)
void gmax2(float* __restrict__ red)
{
    float m = -3.4e38f;
    for (int i = threadIdx.x; i < 1024; i += 256) m = fmaxf(m, red[256 + i]);
    #pragma unroll
    for (int off = 32; off; off >>= 1) m = fmaxf(m, __shfl_down(m, off, 64));
    __shared__ float sm[4];
    const int wid = threadIdx.x >> 6, lane = threadIdx.x & 63;
    if (lane == 0) sm[wid] = m;
    __syncthreads();
    if (threadIdx.x == 0) red[0] = fmaxf(fmaxf(sm[0], sm[1]), fmaxf(sm[2], sm[3]));
}

// phi_kT = bf16(exp(pkT - gmax)/16)
__global__ __launch_bounds__(256)
void phikT_exp(const float* __restrict__ P, const float* __restrict__ red,
               ushort_t* __restrict__ out)
{
    const long long i = (long long)blockIdx.x * 256 + threadIdx.x;
    out[i] = f2bf(expf(P[i] - red[0]) * 0.0625f);
}

// ksum[b,m] = sum_l phi_kT[m, b*L+l]; one block per (b,m)
__global__ __launch_bounds__(256)
void ksum_k(const ushort_t* __restrict__ phikT, float* __restrict__ ks)
{
    const int b = blockIdx.x >> 8, m = blockIdx.x & 255;
    const ushort_t* p = phikT + (long long)m * N_ + b * L_;
    uint4 u = *(const uint4*)(p + threadIdx.x * 8);
    const uint_t w[4] = {u.x, u.y, u.z, u.w};
    float s = 0.f;
    #pragma unroll
    for (int q = 0; q < 4; ++q)
        s += bf2f((ushort_t)(w[q] & 0xffff)) + bf2f((ushort_t)(w[q] >> 16));
    #pragma unroll
    for (int off = 32; off; off >>= 1) s += __shfl_down(s, off, 64);
    __shared__ float sm[4];
    const int wid = threadIdx.x >> 6, lane = threadIdx.x & 63;
    if (lane == 0) sm[wid] = s;
    __syncthreads();
    if (threadIdx.x == 0)
        ks[blockIdx.x] = sm[0] + sm[1] + sm[2] + sm[3];
}

// den[n] = sum_m phi_q_bf[n,m]*ksum[b,m]; one wave per row
__global__ __launch_bounds__(256)
void den_k(const ushort_t* __restrict__ phiq, const float* __restrict__ ks,
           float* __restrict__ den)
{
    const int wid = threadIdx.x >> 6, lane = threadIdx.x & 63;
    const long long n = (long long)blockIdx.x * 4 + wid;
    const int b = (int)(n >> 11);
    uint2 u = *(const uint2*)(phiq + n * M_ + lane * 4);
    float4 kk = *(const float4*)(ks + b * M_ + lane * 4);
    float s = bf2f((ushort_t)(u.x & 0xffff)) * kk.x
            + bf2f((ushort_t)(u.x >> 16)) * kk.y
            + bf2f((ushort_t)(u.y & 0xffff)) * kk.z
            + bf2f((ushort_t)(u.y >> 16)) * kk.w;
    #pragma unroll
    for (int off = 32; off; off >>= 1) s += __shfl_down(s, off, 64);
    if (lane == 0) den[n] = s;
}

// zst_bf chunk = bf16(modrelu(z + yo)); zr/zi/out pre-offset; yo chunk-local
__global__ __launch_bounds__(256)
void modrelu_attn(const float* __restrict__ zr, const float* __restrict__ zi,
                  const float* __restrict__ yo, const float* __restrict__ b_attn,
                  ushort_t* __restrict__ zst)
{
    const long long t = (long long)blockIdx.x * 256 + threadIdx.x;
    const long long n = t >> 9; const int d = (int)(t & 511);
    const float ar = zr[t] + yo[n * D2_ + d];
    const float ai = zi[t] + yo[n * D2_ + D_ + d];
    const float mag = sqrtf(ar * ar + ai * ai + EPS_);
    const float s = fmaxf(mag + b_attn[d], 0.f) / mag;
    zst[n * D2_ + d]      = f2bf(ar * s);
    zst[n * D2_ + D_ + d] = f2bf(ai * s);
}

// out chunk = modrelu(zst + f) interleaved; zst(bf16)/f/out pre-offset
__global__ __launch_bounds__(256)
void modrelu_out(const ushort_t* __restrict__ zst, const float* __restrict__ f,
                 const float* __restrict__ b_ffn, float* __restrict__ out)
{
    const long long t = (long long)blockIdx.x * 256 + threadIdx.x;
    const long long n = t >> 9; const int d = (int)(t & 511);
    const float ar = bf2f(zst[n * D2_ + d])      + f[n * D2_ + d];
    const float ai = bf2f(zst[n * D2_ + D_ + d]) + f[n * D2_ + D_ + d];
    const float mag = sqrtf(ar * ar + ai * ai + EPS_);
    const float s = fmaxf(mag + b_ffn[d], 0.f) / mag;
    out[t * 2]     = ar * s;
    out[t * 2 + 1] = ai * s;
}

extern "C" void kernel_launch(void* const* d_in, const int* in_sizes, int n_in,
                              void* d_out, int out_size, void* d_ws, size_t ws_size,
                              hipStream_t stream)
{
    const float* zr    = (const float*)d_in[0];
    const float* zi    = (const float*)d_in[1];
    const float* Wq    = (const float*)d_in[2];
    const float* Wk    = (const float*)d_in[3];
    const float* Wv    = (const float*)d_in[4];
    const float* Wo    = (const float*)d_in[5];
    const float* Wf    = (const float*)d_in[6];
    const float* b_attn= (const float*)d_in[7];
    const float* W1r   = (const float*)d_in[8];
    const float* W1i   = (const float*)d_in[9];
    const float* b1r   = (const float*)d_in[10];
    const float* b1i   = (const float*)d_in[11];
    const float* W2r   = (const float*)d_in[12];
    const float* W2i   = (const float*)d_in[13];
    const float* b2r   = (const float*)d_in[14];
    const float* b2i   = (const float*)d_in[15];
    const float* b_ffn = (const float*)d_in[16];

    char* w = (char*)d_ws;
    // Layout (124.0 MB peak; round-2 proved >=130.3 MB is safe):
    // P doubles as: pq/pkT (16.8 MB) -> yo 8192-row fp32 chunk (33.5 MB) ->
    // f 4096-row fp32 chunk. WqT/WkT/WvT/Wfb live in P's second half (dead
    // before yo clobbers them). WoT survives until yo -> separate.
    ushort_t* Xbf = (ushort_t*)(w + 0LL);          // x_bf -> zst_bf (33.55 MB)
    ushort_t* A1  = (ushort_t*)(w + 33554432LL);   // q/k -> vT -> y -> h (33.55 MB)
    float*    P   = (float*)   (w + 67108864LL);   // 33.55 MB region
    ushort_t* WqT = (ushort_t*)(w + 83886080LL);   // P+16.8M
    ushort_t* WkT = (ushort_t*)(w + 85983232LL);
    ushort_t* WvT = (ushort_t*)(w + 88080384LL);
    ushort_t* Wfb = (ushort_t*)(w + 90177536LL);   // ends 90.7M < F1
    ushort_t* F1  = (ushort_t*)(w + 100663296LL);  // phi_q_bf -> wc1T (8.39 MB)
    ushort_t* F2  = (ushort_t*)(w + 109051904LL);  // phi_kT -> wc2T (8.39 MB)
    ushort_t* WoT = (ushort_t*)(w + 117440512LL);  // 2 MB
    ushort_t* KVT = (ushort_t*)(w + 119537664LL);  // (8,1024,256) bf16, 4 MB
    float* ssqq = (float*)(w + 123731968LL);
    float* ssqk = (float*)(w + 123797504LL);
    float* den  = (float*)(w + 123863040LL);
    float* ksum = (float*)(w + 123928576LL);
    float* red  = (float*)(w + 123936768LL);
    float* bc1  = (float*)(w + 123944960LL);
    float* bc2  = (float*)(w + 123961344LL);

    const float scl = 0.1767766952966369f;  // D2^-0.25
    dim3 blk(256);

    auto GM = [&](const ushort_t* A, const ushort_t* Bm, void* C,
                  int rows, int cols, int K, int lda, int ldb, int ldc,
                  long long sA, long long sB, long long sC, int nb,
                  int epi, float alpha, const float* aux, int auxStride,
                  const float* bias, int obf) {
        dim3 grid(cols / 128, rows / 128, nb);
        gemm_mfma<<<grid, blk, 0, stream>>>(A, Bm, C, K, lda, ldb, ldc,
                                            sA, sB, sC, epi, alpha, aux,
                                            auxStride, bias, obf);
    };

    // ---- one-time weight prep + input convert ----
    transpose_cvt_sq<<<dim3(32, 32), blk, 0, stream>>>(Wq, WqT);
    transpose_cvt_sq<<<dim3(32, 32), blk, 0, stream>>>(Wk, WkT);
    transpose_cvt_sq<<<dim3(32, 32), blk, 0, stream>>>(Wv, WvT);
    transpose_cvt_sq<<<dim3(32, 32), blk, 0, stream>>>(Wo, WoT);
    cvt_Wf<<<1024, blk, 0, stream>>>(Wf, Wfb);
    build_bias<<<16, blk, 0, stream>>>(b1r, b1i, b2r, b2i, bc1, bc2);
    cvt_x<<<N_ * (D2_ / 4) / 256, blk, 0, stream>>>(zr, zi, Xbf);

    // ---- q phase: q_bf = x@WqT*scl; ssqq; pq = q@Wf^T - 0.5ssqq; phi_q ----
    GM(Xbf, WqT, A1, N_, D2_, D2_, D2_, D2_, D2_, 0, 0, 0, 1, 0, scl, nullptr, 0, nullptr, 1);
    rowsumsq_bf<<<N_ / 4, blk, 0, stream>>>(A1, ssqq);
    GM(A1, Wfb, P, N_, M_, D2_, D2_, D2_, M_, 0, 0, 0, 1, 1, 1.f, ssqq, 0, nullptr, 0);
    phi_rowmax_exp<<<N_, blk, 0, stream>>>(P, F1);

    // ---- k phase: k_bf; ssqk; pkT = Wf@k^T - 0.5ssqk[col]; phi_kT ----
    GM(Xbf, WkT, A1, N_, D2_, D2_, D2_, D2_, D2_, 0, 0, 0, 1, 0, scl, nullptr, 0, nullptr, 1);
    rowsumsq_bf<<<N_ / 4, blk, 0, stream>>>(A1, ssqk);
    GM(Wfb, A1, P, M_, N_, D2_, D2_, D2_, N_, 0, 0, 0, 1, 5, 1.f, ssqk, 0, nullptr, 0);
    gmax1<<<1024, blk, 0, stream>>>(P, red + 256, M_ * N_);
    gmax2<<<1, blk, 0, stream>>>(red);
    phikT_exp<<<M_ * N_ / 256, blk, 0, stream>>>(P, red, F2);

    // ---- vT = Wv^T @ x^T (1024 x 16384) ----
    GM(WvT, Xbf, A1, D2_, N_, D2_, D2_, D2_, N_, 0, 0, 0, 1, 0, 1.f, nullptr, 0, nullptr, 1);

    // ---- ksum; kvT[b] = vT_b @ phi_kT_b^T (1024 x 256, K=L) ----
    ksum_k<<<B_ * M_, blk, 0, stream>>>(F2, ksum);
    GM(A1, F2, KVT, D2_, M_, L_, N_, N_, M_, L_, L_, (long long)D2_ * M_, B_,
       0, 1.f, nullptr, 0, nullptr, 1);

    // ---- den; y_bf[b] = phi_q_b @ kvT_b^T / (den+eps) ----
    den_k<<<N_ / 4, blk, 0, stream>>>(F1, ksum, den);
    GM(F1, KVT, A1, L_, D2_, M_, M_, M_, D2_, (long long)L_ * M_,
       (long long)D2_ * M_, (long long)L_ * D2_, B_, 2, 1.f, den, L_, nullptr, 1);

    // ---- yo + attn modrelu, 2 chunks of 8192 rows (grid 512 = 2/CU) ----
    for (int c = 0; c < 2; ++c) {
        const long long ro = (long long)c * 8192;
        GM(A1 + ro * D2_, WoT, P, 8192, D2_, D2_, D2_, D2_, D2_, 0, 0, 0, 1,
           0, 1.f, nullptr, 0, nullptr, 0);
        modrelu_attn<<<8192 * D_ / 256, blk, 0, stream>>>(
            zr + ro * D_, zi + ro * D_, P, b_attn, Xbf + ro * D2_);
    }

    // ---- combined FFN weights into F1/F2 (phi buffers dead) ----
    build_wc1T<<<dim3(32, 128), blk, 0, stream>>>(W1r, W1i, F1);
    build_wc2T<<<dim3(128, 32), blk, 0, stream>>>(W2r, W2i, F2);

    // ---- FFN + final modrelu, 4 chunks of 4096 (h chunk lives in A1) ----
    for (int c = 0; c < 4; ++c) {
        const long long ro = (long long)c * 4096;
        GM(Xbf + ro * D2_, F1, A1, 4096, 2 * H_, D2_, D2_, D2_, 2 * H_,
           0, 0, 0, 1, 3, 1.f, nullptr, 0, bc1, 1);
        GM(A1, F2, P, 4096, D2_, 2 * H_, 2 * H_, 2 * H_, D2_,
           0, 0, 0, 1, 4, 1.f, nullptr, 0, bc2, 0);
        modrelu_out<<<4096 * D_ / 256, blk, 0, stream>>>(
            Xbf + ro * D2_, P, b_ffn, (float*)d_out + ro * D2_);
    }

    (void)in_sizes; (void)n_in; (void)out_size; (void)ws_size;
}

// Round 6
// 1147.483 us; speedup vs baseline: 8.4345x; 1.1506x over previous
//
#include <hip/hip_runtime.h>
#include <math.h>

#define B_ 8
#define L_ 2048
#define D_ 512
#define M_ 256
#define D2_ 1024
#define H_ 2048
#define N_ 16384          // B_*L_
#define EPS_ 1e-6f

typedef __attribute__((ext_vector_type(8))) short bf16x8;
typedef __attribute__((ext_vector_type(4))) float f32x4;
typedef unsigned short ushort_t;
typedef unsigned int uint_t;

// s_waitcnt immediates (gfx9 encoding): lgkmcnt=0xF(no wait), expcnt=7(no wait)
#define WAITCNT_VM8 0x0F78
#define WAITCNT_VM4 0x0F74
#define WAITCNT_VM0 0x0F70

__device__ __forceinline__ ushort_t f2bf(float f) {
    uint_t u = __float_as_uint(f);
    u += 0x7FFFu + ((u >> 16) & 1u);        // round-to-nearest-even
    return (ushort_t)(u >> 16);
}
__device__ __forceinline__ float bf2f(ushort_t u) {
    return __uint_as_float(((uint_t)u) << 16);
}
__device__ __forceinline__ void gload_lds16(const void* g, void* l) {
    __builtin_amdgcn_global_load_lds(
        (const __attribute__((address_space(1))) void*)g,
        (__attribute__((address_space(3))) void*)l, 16, 0, 0);
}

// ---------------------------------------------------------------------------
// bf16 MFMA GEMM: 128x128 tile, BK=32, 256 thr = 2x2 waves, 4x4 16x16x32 MFMA
// per wave. A:(rows x K) K-contig bf16, B:(cols x K) K-contig bf16.
// 4-buffer pipeline, prefetch DISTANCE 2, ONE barrier per K-step:
//   iter t: issue(t+2) -> s_waitcnt vmcnt(8) (tile t landed; t+1,t+2 in
//   flight) -> s_barrier -> compute from buf t&3.
// Buffer t&3 is rewritten by issue(t+4) in iter t+2, i.e. after iter t+1's
// barrier, which every wave reaches only after finishing compute(t) -> the
// trailing barrier of the classic 2-barrier K-loop is provably unnecessary.
// Depth-2 prefetch (~2 iter bodies) covers the ~900cyc HBM-miss latency that
// capped round-5's depth-1 dbuf at MfmaUtil 14%.
// LDS k-chunk XOR swizzle (round-3): staging lane l takes global k-chunk
// (l&3)^((l>>3)&3); fragment reads use (fq^((fr>>1)&3)) -> 0 bank conflicts.
// Epilogues: 0:*alpha 1:-0.5*aux[row] 5:-0.5*aux[col] 2:/(aux[row]+EPS)
//            3:relu(+bias[col]) 4:+bias[col].  obf: 1 bf16 out, 0 fp32 out.
// Batched via blockIdx.z (element strides sA/sB/sC); aux idx = bz*auxStride+.
// rows, cols % 128 == 0; K % 32 == 0.
// ---------------------------------------------------------------------------
__global__ __launch_bounds__(256)
void gemm_mfma(const ushort_t* __restrict__ A, const ushort_t* __restrict__ Bm,
               void* __restrict__ Cp, int K, int lda, int ldb, int ldc,
               long long sA, long long sB, long long sC,
               int epi, float alpha, const float* __restrict__ aux,
               int auxStride, const float* __restrict__ bias, int obf)
{
    __shared__ ushort_t As[4][128 * 32];
    __shared__ ushort_t Bs[4][128 * 32];

    const int bz = blockIdx.z;
    A  += (long long)bz * sA;
    Bm += (long long)bz * sB;
    const int row0 = blockIdx.y * 128;
    const int col0 = blockIdx.x * 128;

    const int tid  = threadIdx.x;
    const int lane = tid & 63;
    const int wave = tid >> 6;
    const int wr = wave >> 1, wc = wave & 1;

    const int srow = tid >> 2;
    const int skol = (((tid & 3) ^ ((tid >> 3) & 3)) * 8);

    f32x4 acc[4][4];
    #pragma unroll
    for (int i = 0; i < 4; ++i)
        #pragma unroll
        for (int j = 0; j < 4; ++j)
            acc[i][j] = (f32x4){0.f, 0.f, 0.f, 0.f};

    const int fr = lane & 15;     // row/col within 16-tile
    const int fq = lane >> 4;     // k-quad
    const int koff = ((fq ^ ((fr >> 1) & 3))) * 8;

    const int nT = K >> 5;

    auto issue = [&](int t) {
        const int buf = t & 3;
        const int k0 = t << 5;
        gload_lds16(A + (long long)(row0 + srow) * lda + k0 + skol,
                    &As[buf][(wave * 16) * 32]);
        gload_lds16(A + (long long)(row0 + 64 + srow) * lda + k0 + skol,
                    &As[buf][(64 + wave * 16) * 32]);
        gload_lds16(Bm + (long long)(col0 + srow) * ldb + k0 + skol,
                    &Bs[buf][(wave * 16) * 32]);
        gload_lds16(Bm + (long long)(col0 + 64 + srow) * ldb + k0 + skol,
                    &Bs[buf][(64 + wave * 16) * 32]);
    };

    issue(0);
    if (nT > 1) issue(1);
    for (int t = 0; t < nT; ++t) {
        if (t + 2 < nT) {
            issue(t + 2);
            __builtin_amdgcn_s_waitcnt(WAITCNT_VM8);   // tile t landed
        } else if (t + 1 < nT) {
            __builtin_amdgcn_s_waitcnt(WAITCNT_VM4);
        } else {
            __builtin_amdgcn_s_waitcnt(WAITCNT_VM0);
        }
        __builtin_amdgcn_s_barrier();

        const int cur = t & 3;
        bf16x8 a[4], b[4];
        #pragma unroll
        for (int i = 0; i < 4; ++i)
            a[i] = *(const bf16x8*)&As[cur][(wr * 64 + i * 16 + fr) * 32 + koff];
        #pragma unroll
        for (int j = 0; j < 4; ++j)
            b[j] = *(const bf16x8*)&Bs[cur][(wc * 64 + j * 16 + fr) * 32 + koff];
        #pragma unroll
        for (int i = 0; i < 4; ++i)
            #pragma unroll
            for (int j = 0; j < 4; ++j)
                acc[i][j] = __builtin_amdgcn_mfma_f32_16x16x32_bf16(
                    a[i], b[j], acc[i][j], 0, 0, 0);
        // no trailing barrier: buf 'cur' rewritten only in iter t+2, behind
        // iter t+1's barrier.
    }

    // epilogue: C/D layout col=lane&15, row=(lane>>4)*4+reg
    const int gr0 = row0 + wr * 64;
    const int gc0 = col0 + wc * 64;
    #pragma unroll
    for (int i = 0; i < 4; ++i) {
        #pragma unroll
        for (int r = 0; r < 4; ++r) {
            const int row = gr0 + i * 16 + fq * 4 + r;
            float raux = 0.f;
            if (epi == 1 || epi == 2) raux = aux[(long long)bz * auxStride + row];
            #pragma unroll
            for (int j = 0; j < 4; ++j) {
                const int col = gc0 + j * 16 + fr;
                float v = acc[i][j][r];
                if (epi == 0)      v *= alpha;
                else if (epi == 1) v -= 0.5f * raux;
                else if (epi == 2) v = v / (raux + EPS_);
                else if (epi == 5) v -= 0.5f * aux[(long long)bz * auxStride + col];
                else if (epi == 3) { v += bias[col]; v = v > 0.f ? v : 0.f; }
                else if (epi == 4) v += bias[col];
                const long long off = (long long)bz * sC + (long long)row * ldc + col;
                if (obf) ((ushort_t*)Cp)[off] = f2bf(v);
                else     ((float*)Cp)[off] = v;
            }
        }
    }
}

// ---------- build / convert kernels ----------------------------------------

// 1024x1024 fp32 W -> bf16 W^T  (out[n][k] = W[k][n])
__global__ __launch_bounds__(256)
void transpose_cvt_sq(const float* __restrict__ W, ushort_t* __restrict__ out)
{
    __shared__ float S[32][33];
    const int tx = threadIdx.x & 31, ty = threadIdx.x >> 5;
    const int n0 = blockIdx.x * 32, k0 = blockIdx.y * 32;
    #pragma unroll
    for (int r = 0; r < 4; ++r)
        S[ty + 8 * r][tx] = W[(long long)(k0 + ty + 8 * r) * 1024 + n0 + tx];
    __syncthreads();
    #pragma unroll
    for (int r = 0; r < 4; ++r)
        out[(long long)(n0 + ty + 8 * r) * 1024 + k0 + tx] = f2bf(S[tx][ty + 8 * r]);
}

// wc1T (4096 x 1024): out[j][i] of combined [[W1r,W1i],[-W1i,W1r]]
__global__ __launch_bounds__(256)
void build_wc1T(const float* __restrict__ W1r, const float* __restrict__ W1i,
                ushort_t* __restrict__ out)
{
    __shared__ float S[32][33];
    const int tx = threadIdx.x & 31, ty = threadIdx.x >> 5;
    const int i0 = blockIdx.x * 32, j0 = blockIdx.y * 32;
    #pragma unroll
    for (int r = 0; r < 4; ++r) {
        const int i = i0 + ty + 8 * r, j = j0 + tx;
        float v;
        if (j < H_) v = (i < D_) ? W1r[(long long)i * H_ + j]
                                 : -W1i[(long long)(i - D_) * H_ + j];
        else {
            const int jj = j - H_;
            v = (i < D_) ? W1i[(long long)i * H_ + jj]
                         : W1r[(long long)(i - D_) * H_ + jj];
        }
        S[tx][ty + 8 * r] = v;
    }
    __syncthreads();
    #pragma unroll
    for (int r = 0; r < 4; ++r)
        out[(long long)(j0 + ty + 8 * r) * 1024 + i0 + tx] = f2bf(S[ty + 8 * r][tx]);
}

// wc2T (1024 x 4096): out[j][i] of combined [[W2r,W2i],[-W2i,W2r]]
__global__ __launch_bounds__(256)
void build_wc2T(const float* __restrict__ W2r, const float* __restrict__ W2i,
                ushort_t* __restrict__ out)
{
    __shared__ float S[32][33];
    const int tx = threadIdx.x & 31, ty = threadIdx.x >> 5;
    const int i0 = blockIdx.x * 32, j0 = blockIdx.y * 32;
    #pragma unroll
    for (int r = 0; r < 4; ++r) {
        const int i = i0 + ty + 8 * r, j = j0 + tx;
        float v;
        if (i < H_) v = (j < D_) ? W2r[(long long)i * D_ + j]
                                 : W2i[(long long)i * D_ + (j - D_)];
        else {
            const int ii = i - H_;
            v = (j < D_) ? -W2i[(long long)ii * D_ + j]
                         : W2r[(long long)ii * D_ + (j - D_)];
        }
        S[tx][ty + 8 * r] = v;
    }
    __syncthreads();
    #pragma unroll
    for (int r = 0; r < 4; ++r)
        out[(long long)(j0 + ty + 8 * r) * 4096 + i0 + tx] = f2bf(S[ty + 8 * r][tx]);
}

__global__ __launch_bounds__(256)
void build_bias(const float* __restrict__ b1r, const float* __restrict__ b1i,
                const float* __restrict__ b2r, const float* __restrict__ b2i,
                float* __restrict__ bc1, float* __restrict__ bc2)
{
    const int t = blockIdx.x * 256 + threadIdx.x;   // grid 16 -> t < 4096
    bc1[t] = (t < H_) ? b1r[t] : b1i[t - H_];
    if (t < D2_) bc2[t] = (t < D_) ? b2r[t] : b2i[t - D_];
}

__global__ __launch_bounds__(256)
void cvt_Wf(const float* __restrict__ Wf, ushort_t* __restrict__ out)
{
    const int t = blockIdx.x * 256 + threadIdx.x;   // 262144
    out[t] = f2bf(Wf[t]);
}

// x_bf (N x D2) = bf16(concat(zr, zi))
__global__ __launch_bounds__(256)
void cvt_x(const float* __restrict__ zr, const float* __restrict__ zi,
           ushort_t* __restrict__ x)
{
    long long t = (long long)blockIdx.x * 256 + threadIdx.x;  // N*D2/4
    long long n = t >> 8;
    int j4 = (int)(t & 255) << 2;
    float4 v;
    if (j4 < D_) v = *(const float4*)(zr + n * D_ + j4);
    else         v = *(const float4*)(zi + n * D_ + (j4 - D_));
    uint2 o;
    o.x = (uint_t)f2bf(v.x) | ((uint_t)f2bf(v.y) << 16);
    o.y = (uint_t)f2bf(v.z) | ((uint_t)f2bf(v.w) << 16);
    *(uint2*)(x + n * D2_ + j4) = o;
}

// ssq[n] = sum_k bf2f(A[n,k])^2, row len 1024, one wave per row
__global__ __launch_bounds__(256)
void rowsumsq_bf(const ushort_t* __restrict__ A, float* __restrict__ out)
{
    const int wid = threadIdx.x >> 6, lane = threadIdx.x & 63;
    const long long row = (long long)blockIdx.x * 4 + wid;
    const ushort_t* a = A + row * D2_;
    float s = 0.f;
    #pragma unroll
    for (int h = 0; h < 2; ++h) {
        uint4 u = *(const uint4*)(a + h * 512 + lane * 8);
        const uint_t w[4] = {u.x, u.y, u.z, u.w};
        #pragma unroll
        for (int p = 0; p < 4; ++p) {
            float lo = bf2f((ushort_t)(w[p] & 0xffff));
            float hi = bf2f((ushort_t)(w[p] >> 16));
            s += lo * lo + hi * hi;
        }
    }
    #pragma unroll
    for (int off = 32; off; off >>= 1) s += __shfl_down(s, off, 64);
    if (lane == 0) out[row] = s;
}

// phi_q: per-row max-subtract + exp over M=256, pq fp32 -> bf16 out
__global__ __launch_bounds__(256)
void phi_rowmax_exp(const float* __restrict__ P, ushort_t* __restrict__ out)
{
    const long long row = blockIdx.x;
    const int t = threadIdx.x;
    const float v = P[row * M_ + t];
    float m = v;
    #pragma unroll
    for (int off = 32; off; off >>= 1) m = fmaxf(m, __shfl_down(m, off, 64));
    __shared__ float sm[4];
    const int wid = t >> 6, lane = t & 63;
    if (lane == 0) sm[wid] = m;
    __syncthreads();
    const float mm = fmaxf(fmaxf(sm[0], sm[1]), fmaxf(sm[2], sm[3]));
    out[row * M_ + t] = f2bf(expf(v - mm) * 0.0625f);
}

__global__ __launch_bounds__(256)
void gmax1(const float* __restrict__ P, float* __restrict__ part, int n)
{
    float m = -3.4e38f;
    for (long long i = (long long)blockIdx.x * 256 + threadIdx.x; i < n;
         i += (long long)gridDim.x * 256)
        m = fmaxf(m, P[i]);
    #pragma unroll
    for (int off = 32; off; off >>= 1) m = fmaxf(m, __shfl_down(m, off, 64));
    __shared__ float sm[4];
    const int wid = threadIdx.x >> 6, lane = threadIdx.x & 63;
    if (lane == 0) sm[wid] = m;
    __syncthreads();
    if (threadIdx.x == 0)
        part[blockIdx.x] = fmaxf(fmaxf(sm[0], sm[1]), fmaxf(sm[2], sm[3]));
}

__global__ __launch_bounds__(256)
void gmax2(float* __restrict__ red)
{
    float m = -3.4e38f;
    for (int i = threadIdx.x; i < 1024; i += 256) m = fmaxf(m, red[256 + i]);
    #pragma unroll
    for (int off = 32; off; off >>= 1) m = fmaxf(m, __shfl_down(m, off, 64));
    __shared__ float sm[4];
    const int wid = threadIdx.x >> 6, lane = threadIdx.x & 63;
    if (lane == 0) sm[wid] = m;
    __syncthreads();
    if (threadIdx.x == 0) red[0] = fmaxf(fmaxf(sm[0], sm[1]), fmaxf(sm[2], sm[3]));
}

// phi_kT = bf16(exp(pkT - gmax)/16)
__global__ __launch_bounds__(256)
void phikT_exp(const float* __restrict__ P, const float* __restrict__ red,
               ushort_t* __restrict__ out)
{
    const long long i = (long long)blockIdx.x * 256 + threadIdx.x;
    out[i] = f2bf(expf(P[i] - red[0]) * 0.0625f);
}

// ksum[b,m] = sum_l phi_kT[m, b*L+l]; one block per (b,m)
__global__ __launch_bounds__(256)
void ksum_k(const ushort_t* __restrict__ phikT, float* __restrict__ ks)
{
    const int b = blockIdx.x >> 8, m = blockIdx.x & 255;
    const ushort_t* p = phikT + (long long)m * N_ + b * L_;
    uint4 u = *(const uint4*)(p + threadIdx.x * 8);
    const uint_t w[4] = {u.x, u.y, u.z, u.w};
    float s = 0.f;
    #pragma unroll
    for (int q = 0; q < 4; ++q)
        s += bf2f((ushort_t)(w[q] & 0xffff)) + bf2f((ushort_t)(w[q] >> 16));
    #pragma unroll
    for (int off = 32; off; off >>= 1) s += __shfl_down(s, off, 64);
    __shared__ float sm[4];
    const int wid = threadIdx.x >> 6, lane = threadIdx.x & 63;
    if (lane == 0) sm[wid] = s;
    __syncthreads();
    if (threadIdx.x == 0)
        ks[blockIdx.x] = sm[0] + sm[1] + sm[2] + sm[3];
}

// den[n] = sum_m phi_q_bf[n,m]*ksum[b,m]; one wave per row
__global__ __launch_bounds__(256)
void den_k(const ushort_t* __restrict__ phiq, const float* __restrict__ ks,
           float* __restrict__ den)
{
    const int wid = threadIdx.x >> 6, lane = threadIdx.x & 63;
    const long long n = (long long)blockIdx.x * 4 + wid;
    const int b = (int)(n >> 11);
    uint2 u = *(const uint2*)(phiq + n * M_ + lane * 4);
    float4 kk = *(const float4*)(ks + b * M_ + lane * 4);
    float s = bf2f((ushort_t)(u.x & 0xffff)) * kk.x
            + bf2f((ushort_t)(u.x >> 16)) * kk.y
            + bf2f((ushort_t)(u.y & 0xffff)) * kk.z
            + bf2f((ushort_t)(u.y >> 16)) * kk.w;
    #pragma unroll
    for (int off = 32; off; off >>= 1) s += __shfl_down(s, off, 64);
    if (lane == 0) den[n] = s;
}

// zst_bf chunk = bf16(modrelu(z + yo)); zr/zi/out pre-offset; yo chunk-local
__global__ __launch_bounds__(256)
void modrelu_attn(const float* __restrict__ zr, const float* __restrict__ zi,
                  const float* __restrict__ yo, const float* __restrict__ b_attn,
                  ushort_t* __restrict__ zst)
{
    const long long t = (long long)blockIdx.x * 256 + threadIdx.x;
    const long long n = t >> 9; const int d = (int)(t & 511);
    const float ar = zr[t] + yo[n * D2_ + d];
    const float ai = zi[t] + yo[n * D2_ + D_ + d];
    const float mag = sqrtf(ar * ar + ai * ai + EPS_);
    const float s = fmaxf(mag + b_attn[d], 0.f) / mag;
    zst[n * D2_ + d]      = f2bf(ar * s);
    zst[n * D2_ + D_ + d] = f2bf(ai * s);
}

// out chunk = modrelu(zst + f) interleaved; zst(bf16)/f/out pre-offset
__global__ __launch_bounds__(256)
void modrelu_out(const ushort_t* __restrict__ zst, const float* __restrict__ f,
                 const float* __restrict__ b_ffn, float* __restrict__ out)
{
    const long long t = (long long)blockIdx.x * 256 + threadIdx.x;
    const long long n = t >> 9; const int d = (int)(t & 511);
    const float ar = bf2f(zst[n * D2_ + d])      + f[n * D2_ + d];
    const float ai = bf2f(zst[n * D2_ + D_ + d]) + f[n * D2_ + D_ + d];
    const float mag = sqrtf(ar * ar + ai * ai + EPS_);
    const float s = fmaxf(mag + b_ffn[d], 0.f) / mag;
    out[t * 2]     = ar * s;
    out[t * 2 + 1] = ai * s;
}

extern "C" void kernel_launch(void* const* d_in, const int* in_sizes, int n_in,
                              void* d_out, int out_size, void* d_ws, size_t ws_size,
                              hipStream_t stream)
{
    const float* zr    = (const float*)d_in[0];
    const float* zi    = (const float*)d_in[1];
    const float* Wq    = (const float*)d_in[2];
    const float* Wk    = (const float*)d_in[3];
    const float* Wv    = (const float*)d_in[4];
    const float* Wo    = (const float*)d_in[5];
    const float* Wf    = (const float*)d_in[6];
    const float* b_attn= (const float*)d_in[7];
    const float* W1r   = (const float*)d_in[8];
    const float* W1i   = (const float*)d_in[9];
    const float* b1r   = (const float*)d_in[10];
    const float* b1i   = (const float*)d_in[11];
    const float* W2r   = (const float*)d_in[12];
    const float* W2i   = (const float*)d_in[13];
    const float* b2r   = (const float*)d_in[14];
    const float* b2i   = (const float*)d_in[15];
    const float* b_ffn = (const float*)d_in[16];

    char* w = (char*)d_ws;
    // Attention-phase layout (as round 5, ~124 MB):
    ushort_t* Xbf = (ushort_t*)(w + 0LL);          // x_bf -> zst_bf (33.55 MB)
    ushort_t* A1  = (ushort_t*)(w + 33554432LL);   // q/k -> vT -> y (33.55 MB)
    float*    P   = (float*)   (w + 67108864LL);   // pq/pkT -> yo chunks (33.55)
    ushort_t* WqT = (ushort_t*)(w + 83886080LL);   // in P's 2nd half (dead then)
    ushort_t* WkT = (ushort_t*)(w + 85983232LL);
    ushort_t* WvT = (ushort_t*)(w + 88080384LL);
    ushort_t* Wfb = (ushort_t*)(w + 90177536LL);
    ushort_t* F1  = (ushort_t*)(w + 100663296LL);  // phi_q_bf -> wc1T (8.39 MB)
    ushort_t* F2  = (ushort_t*)(w + 109051904LL);  // phi_kT -> wc2T (8.39 MB)
    ushort_t* WoT = (ushort_t*)(w + 117440512LL);  // 2 MB
    ushort_t* KVT = (ushort_t*)(w + 119537664LL);  // (8,1024,256) bf16, 4 MB
    float* ssqq = (float*)(w + 123731968LL);
    float* ssqk = (float*)(w + 123797504LL);
    float* den  = (float*)(w + 123863040LL);
    float* ksum = (float*)(w + 123928576LL);
    float* red  = (float*)(w + 123936768LL);

    // FFN-phase layout, gated on ws_size:
    //  big mode (ws >= 152 MB): RCH=8192; h bf16 (64 MB) at 33.55..100.66 MB,
    //   f fp32 (32 MB) at 117.44..150.99 MB (WoT/KVT/smalls dead), bc after f.
    //  small mode: round-5 layout (RCH=4096, h in A1, f in P, bc at 123.9 MB).
    const bool big = ws_size >= 152000000ULL;
    const int  RCH = big ? 8192 : 4096;
    ushort_t* Hb = (ushort_t*)(w + 33554432LL);
    float* Fb  = big ? (float*)(w + 117440512LL) : (float*)(w + 67108864LL);
    float* bc1 = big ? (float*)(w + 150994944LL) : (float*)(w + 123944960LL);
    float* bc2 = big ? (float*)(w + 151011328LL) : (float*)(w + 123961344LL);

    const float scl = 0.1767766952966369f;  // D2^-0.25
    dim3 blk(256);

    auto GM = [&](const ushort_t* A, const ushort_t* Bm, void* C,
                  int rows, int cols, int K, int lda, int ldb, int ldc,
                  long long sA, long long sB, long long sC, int nb,
                  int epi, float alpha, const float* aux, int auxStride,
                  const float* bias, int obf) {
        dim3 grid(cols / 128, rows / 128, nb);
        gemm_mfma<<<grid, blk, 0, stream>>>(A, Bm, C, K, lda, ldb, ldc,
                                            sA, sB, sC, epi, alpha, aux,
                                            auxStride, bias, obf);
    };

    // ---- one-time weight prep + input convert ----
    transpose_cvt_sq<<<dim3(32, 32), blk, 0, stream>>>(Wq, WqT);
    transpose_cvt_sq<<<dim3(32, 32), blk, 0, stream>>>(Wk, WkT);
    transpose_cvt_sq<<<dim3(32, 32), blk, 0, stream>>>(Wv, WvT);
    transpose_cvt_sq<<<dim3(32, 32), blk, 0, stream>>>(Wo, WoT);
    cvt_Wf<<<1024, blk, 0, stream>>>(Wf, Wfb);
    build_bias<<<16, blk, 0, stream>>>(b1r, b1i, b2r, b2i, bc1, bc2);
    cvt_x<<<N_ * (D2_ / 4) / 256, blk, 0, stream>>>(zr, zi, Xbf);

    // ---- q phase: q_bf = x@WqT*scl; ssqq; pq = q@Wf^T - 0.5ssqq; phi_q ----
    GM(Xbf, WqT, A1, N_, D2_, D2_, D2_, D2_, D2_, 0, 0, 0, 1, 0, scl, nullptr, 0, nullptr, 1);
    rowsumsq_bf<<<N_ / 4, blk, 0, stream>>>(A1, ssqq);
    GM(A1, Wfb, P, N_, M_, D2_, D2_, D2_, M_, 0, 0, 0, 1, 1, 1.f, ssqq, 0, nullptr, 0);
    phi_rowmax_exp<<<N_, blk, 0, stream>>>(P, F1);

    // ---- k phase: k_bf; ssqk; pkT = Wf@k^T - 0.5ssqk[col]; phi_kT ----
    GM(Xbf, WkT, A1, N_, D2_, D2_, D2_, D2_, D2_, 0, 0, 0, 1, 0, scl, nullptr, 0, nullptr, 1);
    rowsumsq_bf<<<N_ / 4, blk, 0, stream>>>(A1, ssqk);
    GM(Wfb, A1, P, M_, N_, D2_, D2_, D2_, N_, 0, 0, 0, 1, 5, 1.f, ssqk, 0, nullptr, 0);
    gmax1<<<1024, blk, 0, stream>>>(P, red + 256, M_ * N_);
    gmax2<<<1, blk, 0, stream>>>(red);
    phikT_exp<<<M_ * N_ / 256, blk, 0, stream>>>(P, red, F2);

    // ---- vT = Wv^T @ x^T (1024 x 16384) ----
    GM(WvT, Xbf, A1, D2_, N_, D2_, D2_, D2_, N_, 0, 0, 0, 1, 0, 1.f, nullptr, 0, nullptr, 1);

    // ---- ksum; kvT[b] = vT_b @ phi_kT_b^T (1024 x 256, K=L) ----
    ksum_k<<<B_ * M_, blk, 0, stream>>>(F2, ksum);
    GM(A1, F2, KVT, D2_, M_, L_, N_, N_, M_, L_, L_, (long long)D2_ * M_, B_,
       0, 1.f, nullptr, 0, nullptr, 1);

    // ---- den; y_bf[b] = phi_q_b @ kvT_b^T / (den+eps) ----
    den_k<<<N_ / 4, blk, 0, stream>>>(F1, ksum, den);
    GM(F1, KVT, A1, L_, D2_, M_, M_, M_, D2_, (long long)L_ * M_,
       (long long)D2_ * M_, (long long)L_ * D2_, B_, 2, 1.f, den, L_, nullptr, 1);

    // ---- yo + attn modrelu, 2 chunks of 8192 rows (grid 512 = 2/CU) ----
    for (int c = 0; c < 2; ++c) {
        const long long ro = (long long)c * 8192;
        GM(A1 + ro * D2_, WoT, P, 8192, D2_, D2_, D2_, D2_, D2_, 0, 0, 0, 1,
           0, 1.f, nullptr, 0, nullptr, 0);
        modrelu_attn<<<8192 * D_ / 256, blk, 0, stream>>>(
            zr + ro * D_, zi + ro * D_, P, b_attn, Xbf + ro * D2_);
    }

    // ---- combined FFN weights into F1/F2 (phi buffers dead) ----
    build_wc1T<<<dim3(32, 128), blk, 0, stream>>>(W1r, W1i, F1);
    build_wc2T<<<dim3(128, 32), blk, 0, stream>>>(W2r, W2i, F2);

    // ---- FFN + final modrelu, N_/RCH chunks ----
    for (int c = 0; c < N_ / RCH; ++c) {
        const long long ro = (long long)c * RCH;
        GM(Xbf + ro * D2_, F1, Hb, RCH, 2 * H_, D2_, D2_, D2_, 2 * H_,
           0, 0, 0, 1, 3, 1.f, nullptr, 0, bc1, 1);
        GM(Hb, F2, Fb, RCH, D2_, 2 * H_, 2 * H_, 2 * H_, D2_,
           0, 0, 0, 1, 4, 1.f, nullptr, 0, bc2, 0);
        modrelu_out<<<RCH * D_ / 256, blk, 0, stream>>>(
            Xbf + ro * D2_, Fb, b_ffn, (float*)d_out + ro * D2_);
    }

    (void)in_sizes; (void)n_in; (void)out_size;
}